// Round 7
// baseline (53983.826 us; speedup 1.0000x reference)
//
#include <hip/hip_runtime.h>
#include <hip/hip_fp16.h>
#include <stdint.h>

// ---------------- problem constants ----------------
#define TT     8000
#define TLOW   800
#define TMEL   80
#define NMEL   80
#define NB     8
#define HD     512
#define LC     20
#define NPRE   256
#define NSS    30

// h broadcast buffers: slot s holds h[s-1]; slot 0 = zeros. per slot: 8 batches x 128 u64 (512 fp16)
#define HB_SLOTS (TT + 1)
#define HB_U64   ((size_t)HB_SLOTS * 8 * 128)
#define HB_BYTES (HB_U64 * 8)
#define CONV_BYTES   ((size_t)NB * TLOW * LC * 4)
#define INTERP_BYTES ((size_t)NB * TT * 4)
#define PREW16_BYTES ((size_t)NPRE * HD * 2)
#define OUTW16_BYTES ((size_t)NSS * NPRE * 2)

typedef __attribute__((ext_vector_type(8))) _Float16 half8;
typedef __attribute__((ext_vector_type(4))) float f32x4;

static __device__ __forceinline__ unsigned short f2h_bits(float f) {
    union { _Float16 h; unsigned short u; } c; c.h = (_Float16)f; return c.u;  // RNE
}
static __device__ __forceinline__ float sigf(float x) {
    x = fminf(30.f, fmaxf(-30.f, x));
    return 1.f / (1.f + __expf(-x));
}
static __device__ __forceinline__ float tanhf_(float x) {
    x = fminf(15.f, fmaxf(-15.f, x));
    float e = __expf(2.f * x);
    return (e - 1.f) / (e + 1.f);
}
static __device__ __forceinline__ half8 mkfrag(unsigned long long a, unsigned long long b) {
    union { unsigned long long q[2]; half8 v; } u; u.q[0] = a; u.q[1] = b; return u.v;
}
static __device__ __forceinline__ f32x4 mfma(half8 a, half8 b, f32x4 c) {
    return __builtin_amdgcn_mfma_f32_16x16x32_f16(a, b, c, 0, 0, 0);
}

// ---------------- single-wave slot poll + LDS stage ----------------
// One wave polls a whole 1024-u64 slot (lane l owns words l+64k), sentinel =
// 0xFFFFFFFF per u32 half (fp16 NaN pair). On success, stages to LDS [8][129].
static __device__ __forceinline__ void poll_stage(const unsigned long long* __restrict__ slot,
                                                  int lane, unsigned long long* __restrict__ st)
{
    unsigned long long v[16];
    for (;;) {
        #pragma unroll
        for (int k = 0; k < 16; k++)
            v[k] = __hip_atomic_load(slot + lane + 64 * k, __ATOMIC_RELAXED, __HIP_MEMORY_SCOPE_AGENT);
        bool bad = false;
        #pragma unroll
        for (int k = 0; k < 16; k++) {
            unsigned int lo = (unsigned int)v[k], hi = (unsigned int)(v[k] >> 32);
            bad |= (lo == 0xFFFFFFFFu) | (hi == 0xFFFFFFFFu);
        }
        if (!__any(bad)) break;
        __builtin_amdgcn_s_sleep(1);
    }
    #pragma unroll
    for (int k = 0; k < 16; k++) {
        int i = lane + 64 * k;
        st[(i >> 7) * 129 + (i & 127)] = v[k];
    }
}
// frag read from staged slot: batch = lane&7 (cols 8-15 mirror, discarded on write)
static __device__ __forceinline__ half8 ldsfrag(const unsigned long long* __restrict__ st,
                                                int lane, int kt)
{
    int base = (lane & 7) * 129 + ((lane >> 4) << 1) + kt * 8;
    return mkfrag(st[base], st[base + 1]);
}

// ---------------- K0: convert pre_w / out_w to fp16 ----------------
__global__ __launch_bounds__(256) void k_prep(
    const float* __restrict__ pre_w, const float* __restrict__ out_w,
    unsigned short* __restrict__ prew16, unsigned short* __restrict__ outw16)
{
    int i = blockIdx.x * 256 + threadIdx.x;
    if (i < NPRE * HD) prew16[i] = f2h_bits(pre_w[i]);
    if (i < NSS * NPRE) outw16[i] = f2h_bits(out_w[i]);
}

// ---------------- K1: conv stack + linear interp (all f32) ----------------
#define CHW 218   // 200 + 2*9 halo (3 conv layers x pad 3)
__global__ __launch_bounds__(256) void k_conv(
    const float* __restrict__ xlow,
    const float* __restrict__ w0, const float* __restrict__ cb0,
    const float* __restrict__ w1, const float* __restrict__ cb1,
    const float* __restrict__ w2, const float* __restrict__ cb2,
    float* __restrict__ convout, float* __restrict__ interp)
{
    int blk = blockIdx.x; int b = blk >> 2; int ch = blk & 3; int cb = ch * 200;
    int tid = threadIdx.x;
    __shared__ float xr[224];
    __shared__ float w0l[LC * 7], w1l[LC * LC * 7], w2l[LC * LC * 7];
    __shared__ float b0l[LC], b1l[LC], b2l[LC];
    __shared__ float h0[LC][CHW], h1[LC][CHW];

    for (int i = tid; i < LC * 7; i += 256) w0l[i] = w0[i];
    for (int i = tid; i < LC * LC * 7; i += 256) { w1l[i] = w1[i]; w2l[i] = w2[i]; }
    for (int i = tid; i < LC; i += 256) { b0l[i] = cb0[i]; b1l[i] = cb1[i]; b2l[i] = cb2[i]; }
    for (int i = tid; i < 224; i += 256) {
        int g = cb - 12 + i;
        xr[i] = (g >= 0 && g < TLOW) ? xlow[b * TLOW + g] : 0.f;
    }
    __syncthreads();
    for (int i = tid; i < LC * CHW; i += 256) {
        int c = i / CHW, s = i - c * CHW;
        int tg = cb - 9 + s;
        float a = b0l[c];
        #pragma unroll
        for (int j = 0; j < 7; j++) a += w0l[c * 7 + j] * xr[s + j];
        h0[c][s] = (tg >= 0 && tg < TLOW) ? tanhf_(a) : 0.f;
    }
    __syncthreads();
    for (int i = tid; i < LC * CHW; i += 256) {
        int c = i / CHW, s = i - c * CHW;
        int tg = cb - 9 + s;
        float a = b1l[c];
        for (int ci = 0; ci < LC; ci++) {
            #pragma unroll
            for (int j = 0; j < 7; j++) {
                int ss = s + j - 3;
                float hv = (ss >= 0 && ss < CHW) ? h0[ci][ss] : 0.f;
                a += w1l[(c * LC + ci) * 7 + j] * hv;
            }
        }
        h1[c][s] = (tg >= 0 && tg < TLOW) ? tanhf_(a) : 0.f;
    }
    __syncthreads();
    for (int i = tid; i < LC * 200; i += 256) {
        int c = i / 200, t0 = i - c * 200; int s = t0 + 9;
        float a = b2l[c];
        for (int ci = 0; ci < LC; ci++) {
            #pragma unroll
            for (int j = 0; j < 7; j++) a += w2l[(c * LC + ci) * 7 + j] * h1[ci][s + j - 3];
        }
        convout[((size_t)b * TLOW + cb + t0) * LC + c] = tanhf_(a);
    }
    for (int i = tid; i < 2000; i += 256) {
        int t = cb * 10 + i;
        float src = ((float)t + 0.5f) * 0.1f - 0.5f;
        src = fminf(fmaxf(src, 0.f), (float)(TLOW - 1));
        int i0 = (int)floorf(src); int i1 = (i0 + 1 < TLOW) ? i0 + 1 : TLOW - 1;
        float w = src - (float)i0;
        interp[(size_t)b * TT + t] = xlow[b * TLOW + i0] * (1.f - w) + xlow[b * TLOW + i1] * w;
    }
}

// ---------------- K2: persistent GRU recurrence ----------------
// grid: 16 blocks x 768 threads (12 waves). blocks 0-7 = layer0 (64 h each),
// blocks 8-15 = layer1. Wave m owns gate tile: gate g=m>>2, rows (m&3)*16+lm.
// Single-wave poll per h-source, staged via LDS; cell over 2 waves; u64 publish.
__global__ __launch_bounds__(768, 1) void k_rnn(
    const float* __restrict__ mel, const float* __restrict__ gsx,
    const float* __restrict__ convout, const float* __restrict__ interp,
    const float* __restrict__ wih0, const float* __restrict__ whh0,
    const float* __restrict__ bih0, const float* __restrict__ bhh0,
    const float* __restrict__ wih1, const float* __restrict__ whh1,
    const float* __restrict__ bih1, const float* __restrict__ bhh1,
    unsigned long long* __restrict__ h0buf, unsigned long long* __restrict__ h1buf)
{
    const int tid = threadIdx.x;
    const int wv = tid >> 6;          // 0..11
    const int lane = tid & 63;
    const int lm = lane & 15, lk = lane >> 4;
    const bool isL0 = (blockIdx.x < 8);
    const int cbid = isL0 ? blockIdx.x : (blockIdx.x - 8);
    const int cb = cbid * 64;                  // h-index chunk base (64 per block)
    const int g  = wv >> 2, ti = wv & 3;       // gate, tile within gate
    const int row = g * 512 + cb + ti * 16 + lm;  // gate weight row for this lane

    __shared__ float exch[3][2][64][9];        // [gate][x/h][row64][batch(pad 9)]
    __shared__ __align__(16) unsigned short xvec[16][136];  // L0 input vector (fp16 bits)
    __shared__ unsigned long long stX[8 * 129]; // staged h0 slot (L1 x-part)
    __shared__ unsigned long long stH[8 * 129]; // staged edge slot (L0: h0; L1: h1)

    // cell lanes: waves 0,1. lane -> batch bb=lane>>3, h rows i0..i0+3 (i0 = wv*32 + (lane&7)*4)
    const int cbb = lane >> 3;
    const int ci0 = wv * 32 + (lane & 7) * 4;  // valid for wv<2
    float hr[4] = {0.f, 0.f, 0.f, 0.f};
    float bi[3][4], bh[3][4];
    {
        const float* bip = isL0 ? bih0 : bih1;
        const float* bhp = isL0 ? bhh0 : bhh1;
        int i0c = (wv < 2) ? ci0 : 0;
        #pragma unroll
        for (int gg = 0; gg < 3; gg++)
            #pragma unroll
            for (int e = 0; e < 4; e++) {
                bi[gg][e] = bip[gg * 512 + cb + i0c + e];
                bh[gg][e] = bhp[gg * 512 + cb + i0c + e];
            }
    }
    for (int i = tid; i < 16 * 136; i += 768) (&xvec[0][0])[i] = 0;

    // publish h[-1] = 0 for own chunk (slot 0): waves 0,1, one u64/lane
    if (wv < 2) {
        unsigned long long* buf = isL0 ? h0buf : h1buf;
        int word = 16 * cbid + 8 * wv + (lane & 7);
        __hip_atomic_store(buf + (size_t)cbb * 128 + word, 0ull,
                           __ATOMIC_RELAXED, __HIP_MEMORY_SCOPE_AGENT);
    }

    if (isL0) {
        // weights in regs: kt 0-3 = input part (K 0..127, cols >=102 zero), kt 4-19 = whh0
        half8 wf[20];
        #pragma unroll
        for (int kt = 0; kt < 20; kt++) {
            #pragma unroll
            for (int j = 0; j < 8; j++) {
                int k = kt * 32 + lk * 8 + j;
                float v;
                if (kt < 4) v = (k < 102) ? wih0[(size_t)row * 102 + k] : 0.f;
                else        v = whh0[(size_t)row * 512 + (k - 128)];
                wf[kt][j] = (_Float16)v;
            }
        }
        // initial xvec(t=0)
        {
            float pf[2];
            #pragma unroll
            for (int u = 0; u < 2; u++) {
                int e = tid + 768 * u; float v = 0.f;
                if (e < 816) {
                    int bb = e / 102, k = e - 102 * bb;
                    if (k < 80)       v = mel[((size_t)bb * TMEL + 0) * NMEL + k];
                    else if (k < 100) v = convout[((size_t)bb * TLOW + 0) * LC + (k - 80)];
                    else if (k == 100) v = interp[(size_t)bb * TT + 0];
                    else               v = gsx[(size_t)bb * TT + 0];
                }
                pf[u] = v;
            }
            #pragma unroll
            for (int u = 0; u < 2; u++) {
                int e = tid + 768 * u;
                if (e < 816) { int bb = e / 102, k = e - 102 * bb; xvec[bb][k] = f2h_bits(pf[u]); }
            }
        }
        __syncthreads();

        for (int t = 0; t < TT; t++) {
            // prefetch x(t+1) (independent; overlaps the poll)
            int tn = (t + 1 < TT) ? (t + 1) : (TT - 1);
            int tmi = tn / 100, tli = tn / 10;
            float pf[2];
            #pragma unroll
            for (int u = 0; u < 2; u++) {
                int e = tid + 768 * u; float v = 0.f;
                if (e < 816) {
                    int bb = e / 102, k = e - 102 * bb;
                    if (k < 80)       v = mel[((size_t)bb * TMEL + tmi) * NMEL + k];
                    else if (k < 100) v = convout[((size_t)bb * TLOW + tli) * LC + (k - 80)];
                    else if (k == 100) v = interp[(size_t)bb * TT + tn];
                    else               v = gsx[(size_t)bb * TT + tn];
                }
                pf[u] = v;
            }

            if (wv == 0) poll_stage(h0buf + (size_t)t * 1024, lane, stH);
            __syncthreads();

            f32x4 accX = {0.f, 0.f, 0.f, 0.f};
            #pragma unroll
            for (int kt = 0; kt < 4; kt++) {
                half8 xf = *(const half8*)&xvec[lm][kt * 32 + lk * 8];
                accX = mfma(wf[kt], xf, accX);
            }
            f32x4 a0 = {0.f, 0.f, 0.f, 0.f}, a1 = {0.f, 0.f, 0.f, 0.f};
            #pragma unroll
            for (int i = 0; i < 8; i++) a0 = mfma(wf[4 + i], ldsfrag(stH, lane, i), a0);
            #pragma unroll
            for (int i = 0; i < 8; i++) a1 = mfma(wf[12 + i], ldsfrag(stH, lane, 8 + i), a1);
            f32x4 accH = a0 + a1;

            if (lm < 8) {
                #pragma unroll
                for (int r2 = 0; r2 < 4; r2++) {
                    exch[g][0][ti * 16 + lk * 4 + r2][lm] = accX[r2];
                    exch[g][1][ti * 16 + lk * 4 + r2][lm] = accH[r2];
                }
            }
            __syncthreads();
            if (wv < 2) {
                unsigned long long pk = 0ull;
                #pragma unroll
                for (int e = 0; e < 4; e++) {
                    int i = ci0 + e;
                    float r = sigf(exch[0][0][i][cbb] + exch[0][1][i][cbb] + bi[0][e] + bh[0][e]);
                    float z = sigf(exch[1][0][i][cbb] + exch[1][1][i][cbb] + bi[1][e] + bh[1][e]);
                    float n = tanhf_(exch[2][0][i][cbb] + bi[2][e] + r * (exch[2][1][i][cbb] + bh[2][e]));
                    hr[e] = (1.f - z) * n + z * hr[e];
                    pk |= ((unsigned long long)f2h_bits(hr[e])) << (16 * e);
                }
                int word = 16 * cbid + 8 * wv + (lane & 7);
                __hip_atomic_store(h0buf + (size_t)(t + 1) * 1024 + (size_t)cbb * 128 + word, pk,
                                   __ATOMIC_RELAXED, __HIP_MEMORY_SCOPE_AGENT);
            }
            #pragma unroll
            for (int u = 0; u < 2; u++) {
                int e = tid + 768 * u;
                if (e < 816) { int bb = e / 102, k = e - 102 * bb; xvec[bb][k] = f2h_bits(pf[u]); }
            }
            __syncthreads();
        }
    } else {
        // layer 1: K = [h0 | h1] concat (1024). kt 0-15 = wih1, kt 16-31 = whh1.
        half8 wf[32];
        #pragma unroll
        for (int kt = 0; kt < 32; kt++) {
            #pragma unroll
            for (int j = 0; j < 8; j++) {
                int k = kt * 32 + lk * 8 + j;
                float v = (kt < 16) ? wih1[(size_t)row * 512 + k]
                                    : whh1[(size_t)row * 512 + (k - 512)];
                wf[kt][j] = (_Float16)v;
            }
        }
        __syncthreads();

        for (int t = 0; t < TT; t++) {
            // parallel polls: wv0 stages h0[t] (slot t+1; L0 runs ahead),
            // wv1 stages h1[t-1] (slot t, the recurrence edge)
            if (wv == 0)      poll_stage(h0buf + (size_t)(t + 1) * 1024, lane, stX);
            else if (wv == 1) poll_stage(h1buf + (size_t)t * 1024,       lane, stH);
            __syncthreads();

            f32x4 x0 = {0.f, 0.f, 0.f, 0.f}, x1 = {0.f, 0.f, 0.f, 0.f};
            #pragma unroll
            for (int i = 0; i < 8; i++) x0 = mfma(wf[i],     ldsfrag(stX, lane, i),     x0);
            #pragma unroll
            for (int i = 0; i < 8; i++) x1 = mfma(wf[8 + i], ldsfrag(stX, lane, 8 + i), x1);
            f32x4 accX = x0 + x1;
            f32x4 a0 = {0.f, 0.f, 0.f, 0.f}, a1 = {0.f, 0.f, 0.f, 0.f};
            #pragma unroll
            for (int i = 0; i < 8; i++) a0 = mfma(wf[16 + i], ldsfrag(stH, lane, i),     a0);
            #pragma unroll
            for (int i = 0; i < 8; i++) a1 = mfma(wf[24 + i], ldsfrag(stH, lane, 8 + i), a1);
            f32x4 accH = a0 + a1;

            if (lm < 8) {
                #pragma unroll
                for (int r2 = 0; r2 < 4; r2++) {
                    exch[g][0][ti * 16 + lk * 4 + r2][lm] = accX[r2];
                    exch[g][1][ti * 16 + lk * 4 + r2][lm] = accH[r2];
                }
            }
            __syncthreads();
            if (wv < 2) {
                unsigned long long pk = 0ull;
                #pragma unroll
                for (int e = 0; e < 4; e++) {
                    int i = ci0 + e;
                    float r = sigf(exch[0][0][i][cbb] + exch[0][1][i][cbb] + bi[0][e] + bh[0][e]);
                    float z = sigf(exch[1][0][i][cbb] + exch[1][1][i][cbb] + bi[1][e] + bh[1][e]);
                    float n = tanhf_(exch[2][0][i][cbb] + bi[2][e] + r * (exch[2][1][i][cbb] + bh[2][e]));
                    hr[e] = (1.f - z) * n + z * hr[e];
                    pk |= ((unsigned long long)f2h_bits(hr[e])) << (16 * e);
                }
                int word = 16 * cbid + 8 * wv + (lane & 7);
                __hip_atomic_store(h1buf + (size_t)(t + 1) * 1024 + (size_t)cbb * 128 + word, pk,
                                   __ATOMIC_RELAXED, __HIP_MEMORY_SCOPE_AGENT);
            }
            __syncthreads();
        }
    }
}

// ---------------- K3: fused head ----------------
__global__ __launch_bounds__(256) void k_final(
    const unsigned long long* __restrict__ h1buf,
    const unsigned short* __restrict__ prew16, const float* __restrict__ pre_b,
    const unsigned short* __restrict__ outw16, const float* __restrict__ out_b,
    float* __restrict__ out)
{
    int blk = blockIdx.x; int b = blk / 125; int tb = (blk - b * 125) * 64;
    int tid = threadIdx.x; int wv = tid >> 6; int l = tid & 63;
    int lm = l & 15, lk = l >> 4;

    half8 af[16];
    int trow = tb + wv * 16 + lm;
    const unsigned long long* abase = h1buf + ((size_t)(trow + 1) * 8 + b) * 128;
    #pragma unroll
    for (int kt = 0; kt < 16; kt++)
        af[kt] = mkfrag(abase[kt * 8 + lk * 2], abase[kt * 8 + lk * 2 + 1]);

    f32x4 acc[16];
    #pragma unroll
    for (int nt = 0; nt < 16; nt++) {
        f32x4 z = {0.f, 0.f, 0.f, 0.f}; acc[nt] = z;
        #pragma unroll
        for (int kt = 0; kt < 16; kt++) {
            int n = nt * 16 + lm; int k = kt * 32 + lk * 8;
            half8 bw = *(const half8*)&prew16[(size_t)n * HD + k];
            acc[nt] = mfma(af[kt], bw, acc[nt]);
        }
    }
    __shared__ __align__(16) unsigned short pt[64][264];
    #pragma unroll
    for (int nt = 0; nt < 16; nt++) {
        float pb = pre_b[nt * 16 + lm];
        #pragma unroll
        for (int r2 = 0; r2 < 4; r2++)
            pt[wv * 16 + lk * 4 + r2][nt * 16 + lm] = f2h_bits(tanhf_(acc[nt][r2] + pb));
    }
    __syncthreads();
    f32x4 a2[2];
    { f32x4 z = {0.f, 0.f, 0.f, 0.f}; a2[0] = z; a2[1] = z; }
    #pragma unroll
    for (int kt = 0; kt < 8; kt++) {
        half8 pa = *(const half8*)&pt[wv * 16 + lm][kt * 32 + lk * 8];
        #pragma unroll
        for (int nt = 0; nt < 2; nt++) {
            int n = nt * 16 + lm;
            half8 bw = (n < NSS) ? *(const half8*)&outw16[(size_t)n * NPRE + kt * 32 + lk * 8]
                                 : mkfrag(0ull, 0ull);
            a2[nt] = mfma(pa, bw, a2[nt]);
        }
    }
    #pragma unroll
    for (int nt = 0; nt < 2; nt++) {
        int n = nt * 16 + lm;
        if (n < NSS) {
            float ob = out_b[n];
            #pragma unroll
            for (int r2 = 0; r2 < 4; r2++) {
                int t = tb + wv * 16 + lk * 4 + r2;
                out[((size_t)b * TT + t) * NSS + n] = a2[nt][r2] + ob;
            }
        }
    }
}

// ---------------- launch ----------------
extern "C" void kernel_launch(void* const* d_in, const int* in_sizes, int n_in,
                              void* d_out, int out_size, void* d_ws, size_t ws_size,
                              hipStream_t stream) {
    const float* mel  = (const float*)d_in[0];
    const float* xlow = (const float*)d_in[1];
    const float* gsx  = (const float*)d_in[2];
    const float* cw0  = (const float*)d_in[3];
    const float* cb0  = (const float*)d_in[4];
    const float* cw1  = (const float*)d_in[5];
    const float* cb1  = (const float*)d_in[6];
    const float* cw2  = (const float*)d_in[7];
    const float* cb2  = (const float*)d_in[8];
    const float* wih0 = (const float*)d_in[9];
    const float* whh0 = (const float*)d_in[10];
    const float* bih0 = (const float*)d_in[11];
    const float* bhh0 = (const float*)d_in[12];
    const float* wih1 = (const float*)d_in[13];
    const float* whh1 = (const float*)d_in[14];
    const float* bih1 = (const float*)d_in[15];
    const float* bhh1 = (const float*)d_in[16];
    const float* prew = (const float*)d_in[17];
    const float* preb = (const float*)d_in[18];
    const float* outw = (const float*)d_in[19];
    const float* outb = (const float*)d_in[20];

    size_t needed = 2 * HB_BYTES + CONV_BYTES + INTERP_BYTES + PREW16_BYTES + OUTW16_BYTES;
    if (ws_size < needed) return;

    char* ws = (char*)d_ws;
    unsigned long long* h0buf = (unsigned long long*)ws;
    unsigned long long* h1buf = (unsigned long long*)(ws + HB_BYTES);
    float* convout = (float*)(ws + 2 * HB_BYTES);
    float* interp  = (float*)(ws + 2 * HB_BYTES + CONV_BYTES);
    unsigned short* prew16 = (unsigned short*)(ws + 2 * HB_BYTES + CONV_BYTES + INTERP_BYTES);
    unsigned short* outw16 = (unsigned short*)(ws + 2 * HB_BYTES + CONV_BYTES + INTERP_BYTES + PREW16_BYTES);

    // sentinel-init both h broadcast buffers (0xFF.. = NaN fp16 pairs / 0xFFFFFFFF u32 sentinel)
    hipMemsetAsync(ws, 0xFF, 2 * HB_BYTES, stream);

    k_prep<<<(NPRE * HD + 255) / 256, 256, 0, stream>>>(prew, outw, prew16, outw16);
    k_conv<<<32, 256, 0, stream>>>(xlow, cw0, cb0, cw1, cb1, cw2, cb2, convout, interp);
    k_rnn<<<16, 768, 0, stream>>>(mel, gsx, convout, interp,
                                  wih0, whh0, bih0, bhh0,
                                  wih1, whh1, bih1, bhh1,
                                  h0buf, h1buf);
    k_final<<<1000, 256, 0, stream>>>(h1buf, prew16, preb, outw16, outb, (float*)d_out);
}

// Round 8
// 23500.540 us; speedup vs baseline: 2.2971x; 2.2971x over previous
//
#include <hip/hip_runtime.h>
#include <hip/hip_fp16.h>
#include <stdint.h>

// ---------------- problem constants ----------------
#define TT     8000
#define TLOW   800
#define TMEL   80
#define NMEL   80
#define NB     8
#define HD     512
#define LC     20
#define NPRE   256
#define NSS    30

// h broadcast buffers: slot s holds h[s-1]; slot 0 = zeros. per slot: 8 batches x 128 u64 (512 fp16)
#define HB_SLOTS (TT + 1)
#define HB_U64   ((size_t)HB_SLOTS * 8 * 128)
#define HB_BYTES (HB_U64 * 8)
#define CONV_BYTES   ((size_t)NB * TLOW * LC * 4)
#define INTERP_BYTES ((size_t)NB * TT * 4)
#define PREW16_BYTES ((size_t)NPRE * HD * 2)
#define OUTW16_BYTES ((size_t)NSS * NPRE * 2)

typedef __attribute__((ext_vector_type(8))) _Float16 half8;
typedef __attribute__((ext_vector_type(4))) float f32x4;

static __device__ __forceinline__ unsigned short f2h_bits(float f) {
    union { _Float16 h; unsigned short u; } c; c.h = (_Float16)f; return c.u;  // RNE
}
static __device__ __forceinline__ float sigf(float x) {
    x = fminf(30.f, fmaxf(-30.f, x));
    return 1.f / (1.f + __expf(-x));
}
static __device__ __forceinline__ float tanhf_(float x) {
    x = fminf(15.f, fmaxf(-15.f, x));
    float e = __expf(2.f * x);
    return (e - 1.f) / (e + 1.f);
}
static __device__ __forceinline__ half8 mkfrag(unsigned long long a, unsigned long long b) {
    union { unsigned long long q[2]; half8 v; } u; u.q[0] = a; u.q[1] = b; return u.v;
}
static __device__ __forceinline__ f32x4 mfma(half8 a, half8 b, f32x4 c) {
    return __builtin_amdgcn_mfma_f32_16x16x32_f16(a, b, c, 0, 0, 0);
}

// ---------------- two-phase slot poll + LDS stage ----------------
// Phase 1: cheap spin on 32 representative u32 words (one per publisher block,
// batch-0 row) -> 128 B per spin iteration instead of 8 KB.
// Phase 2: bulk load the 1024-u64 slot + full sentinel verify (publisher lanes
// store in a single instruction, so stragglers are rare); hot retry.
// Stage to LDS [8][129] (pad breaks batch-stride bank aliasing on frag reads).
static __device__ __forceinline__ void poll_stage(const unsigned long long* __restrict__ slot,
                                                  int lane, unsigned long long* __restrict__ st)
{
    const unsigned int* s32 = (const unsigned int*)slot;
    for (;;) {
        unsigned int w = 0u;
        if (lane < 32)
            w = __hip_atomic_load(s32 + lane * 8, __ATOMIC_RELAXED, __HIP_MEMORY_SCOPE_AGENT);
        if (!__any(w == 0xFFFFFFFFu)) break;
        __builtin_amdgcn_s_sleep(1);
    }
    unsigned long long v[16];
    for (;;) {
        #pragma unroll
        for (int k = 0; k < 16; k++)
            v[k] = __hip_atomic_load(slot + lane + 64 * k, __ATOMIC_RELAXED, __HIP_MEMORY_SCOPE_AGENT);
        bool bad = false;
        #pragma unroll
        for (int k = 0; k < 16; k++) {
            unsigned int lo = (unsigned int)v[k], hi = (unsigned int)(v[k] >> 32);
            bad |= (lo == 0xFFFFFFFFu) | (hi == 0xFFFFFFFFu);
        }
        if (!__any(bad)) break;   // hot retry (no sleep): publish is imminent
    }
    #pragma unroll
    for (int k = 0; k < 16; k++) {
        int i = lane + 64 * k;
        st[(i >> 7) * 129 + (i & 127)] = v[k];
    }
}
// frag read from staged slot: batch = lane&7 (cols 8-15 mirror, discarded on write)
static __device__ __forceinline__ half8 ldsfrag(const unsigned long long* __restrict__ st,
                                                int lane, int kt)
{
    int base = (lane & 7) * 129 + ((lane >> 4) << 1) + kt * 8;
    return mkfrag(st[base], st[base + 1]);
}

// ---------------- K0: convert pre_w / out_w to fp16 ----------------
__global__ __launch_bounds__(256) void k_prep(
    const float* __restrict__ pre_w, const float* __restrict__ out_w,
    unsigned short* __restrict__ prew16, unsigned short* __restrict__ outw16)
{
    int i = blockIdx.x * 256 + threadIdx.x;
    if (i < NPRE * HD) prew16[i] = f2h_bits(pre_w[i]);
    if (i < NSS * NPRE) outw16[i] = f2h_bits(out_w[i]);
}

// ---------------- K1: conv stack + linear interp (all f32) ----------------
#define CHW 218   // 200 + 2*9 halo (3 conv layers x pad 3)
__global__ __launch_bounds__(256) void k_conv(
    const float* __restrict__ xlow,
    const float* __restrict__ w0, const float* __restrict__ cb0,
    const float* __restrict__ w1, const float* __restrict__ cb1,
    const float* __restrict__ w2, const float* __restrict__ cb2,
    float* __restrict__ convout, float* __restrict__ interp)
{
    int blk = blockIdx.x; int b = blk >> 2; int ch = blk & 3; int cb = ch * 200;
    int tid = threadIdx.x;
    __shared__ float xr[224];
    __shared__ float w0l[LC * 7], w1l[LC * LC * 7], w2l[LC * LC * 7];
    __shared__ float b0l[LC], b1l[LC], b2l[LC];
    __shared__ float h0[LC][CHW], h1[LC][CHW];

    for (int i = tid; i < LC * 7; i += 256) w0l[i] = w0[i];
    for (int i = tid; i < LC * LC * 7; i += 256) { w1l[i] = w1[i]; w2l[i] = w2[i]; }
    for (int i = tid; i < LC; i += 256) { b0l[i] = cb0[i]; b1l[i] = cb1[i]; b2l[i] = cb2[i]; }
    for (int i = tid; i < 224; i += 256) {
        int g = cb - 12 + i;
        xr[i] = (g >= 0 && g < TLOW) ? xlow[b * TLOW + g] : 0.f;
    }
    __syncthreads();
    for (int i = tid; i < LC * CHW; i += 256) {
        int c = i / CHW, s = i - c * CHW;
        int tg = cb - 9 + s;
        float a = b0l[c];
        #pragma unroll
        for (int j = 0; j < 7; j++) a += w0l[c * 7 + j] * xr[s + j];
        h0[c][s] = (tg >= 0 && tg < TLOW) ? tanhf_(a) : 0.f;
    }
    __syncthreads();
    for (int i = tid; i < LC * CHW; i += 256) {
        int c = i / CHW, s = i - c * CHW;
        int tg = cb - 9 + s;
        float a = b1l[c];
        for (int ci = 0; ci < LC; ci++) {
            #pragma unroll
            for (int j = 0; j < 7; j++) {
                int ss = s + j - 3;
                float hv = (ss >= 0 && ss < CHW) ? h0[ci][ss] : 0.f;
                a += w1l[(c * LC + ci) * 7 + j] * hv;
            }
        }
        h1[c][s] = (tg >= 0 && tg < TLOW) ? tanhf_(a) : 0.f;
    }
    __syncthreads();
    for (int i = tid; i < LC * 200; i += 256) {
        int c = i / 200, t0 = i - c * 200; int s = t0 + 9;
        float a = b2l[c];
        for (int ci = 0; ci < LC; ci++) {
            #pragma unroll
            for (int j = 0; j < 7; j++) a += w2l[(c * LC + ci) * 7 + j] * h1[ci][s + j - 3];
        }
        convout[((size_t)b * TLOW + cb + t0) * LC + c] = tanhf_(a);
    }
    for (int i = tid; i < 2000; i += 256) {
        int t = cb * 10 + i;
        float src = ((float)t + 0.5f) * 0.1f - 0.5f;
        src = fminf(fmaxf(src, 0.f), (float)(TLOW - 1));
        int i0 = (int)floorf(src); int i1 = (i0 + 1 < TLOW) ? i0 + 1 : TLOW - 1;
        float w = src - (float)i0;
        interp[(size_t)b * TT + t] = xlow[b * TLOW + i0] * (1.f - w) + xlow[b * TLOW + i1] * w;
    }
}

// ---------------- K2: persistent GRU recurrence ----------------
// grid: 64 blocks x 192 threads (round-6 geometry: weights stay in registers).
// blocks 0-31 = layer0 chunks (16 h each), 32-63 = layer1 chunks.
// 2 barriers/step: B1 after poll+stage, B2 after MFMA+exch; cell+publish after B2.
__global__ __launch_bounds__(192, 1) void k_rnn(
    const float* __restrict__ mel, const float* __restrict__ gsx,
    const float* __restrict__ convout, const float* __restrict__ interp,
    const float* __restrict__ wih0, const float* __restrict__ whh0,
    const float* __restrict__ bih0, const float* __restrict__ bhh0,
    const float* __restrict__ wih1, const float* __restrict__ whh1,
    const float* __restrict__ bih1, const float* __restrict__ bhh1,
    unsigned long long* __restrict__ h0buf, unsigned long long* __restrict__ h1buf)
{
    const int tid = threadIdx.x;
    const int wv = tid >> 6;          // 0..2 : gate (r,z,n)
    const int lane = tid & 63;
    const int lm = lane & 15, lk = lane >> 4;
    const bool isL0 = (blockIdx.x < 32);
    const int cbid = isL0 ? blockIdx.x : (blockIdx.x - 32);
    const int cb = cbid * 16;                  // h-index chunk base
    const int row = wv * 512 + cb + lm;        // gate weight row for this lane

    __shared__ float exch[3][2][16][9];        // [gate][x/h][row][batch(pad 9)]
    __shared__ __align__(16) unsigned short xv[2][16][136];  // L0 input, double-buffered
    __shared__ unsigned long long stX[8 * 129]; // staged h0 slot (L1 x-part)
    __shared__ unsigned long long stH[8 * 129]; // staged edge slot (L0: h0; L1: h1)

    // cell lanes (wv0, 64 lanes): batch bb = lane>>3, rows i0=2*(lane&7), i1=i0+1
    const int cbb = lane >> 3;
    const int ci0 = (lane & 7) * 2, ci1 = ci0 + 1;
    float hr0 = 0.f, hr1 = 0.f;                // f32 recurrence state (registers)
    float bi0[3], bi1[3], bh0[3], bh1[3];
    {
        const float* bi = isL0 ? bih0 : bih1;
        const float* bh = isL0 ? bhh0 : bhh1;
        #pragma unroll
        for (int g = 0; g < 3; g++) {
            bi0[g] = bi[g * 512 + cb + ci0]; bi1[g] = bi[g * 512 + cb + ci1];
            bh0[g] = bh[g * 512 + cb + ci0]; bh1[g] = bh[g * 512 + cb + ci1];
        }
    }
    for (int i = tid; i < 2 * 16 * 136; i += 192) (&xv[0][0][0])[i] = 0;

    // publish h[-1] = 0 for own chunk (slot 0): 64 u32 stores by wv0
    {
        unsigned long long* buf = isL0 ? h0buf : h1buf;
        if (wv == 0) {
            unsigned int* o32 = (unsigned int*)buf + (size_t)cbb * 256 + (cb >> 1) + (lane & 7);
            __hip_atomic_store(o32, 0u, __ATOMIC_RELAXED, __HIP_MEMORY_SCOPE_AGENT);
        }
    }

    if (isL0) {
        // weights in regs: kt 0-3 = input part (K 0..127, cols >=102 zero), kt 4-19 = whh0
        half8 wf[20];
        #pragma unroll
        for (int kt = 0; kt < 20; kt++) {
            #pragma unroll
            for (int j = 0; j < 8; j++) {
                int k = kt * 32 + lk * 8 + j;
                float v;
                if (kt < 4) v = (k < 102) ? wih0[(size_t)row * 102 + k] : 0.f;
                else        v = whh0[(size_t)row * 512 + (k - 128)];
                wf[kt][j] = (_Float16)v;
            }
        }
        // initial xv[0] = x(0)
        {
            float pf[5];
            #pragma unroll
            for (int u = 0; u < 5; u++) {
                int e = tid + 192 * u; float v = 0.f;
                if (e < 816) {
                    int bb = e / 102, k = e - 102 * bb;
                    if (k < 80)       v = mel[((size_t)bb * TMEL + 0) * NMEL + k];
                    else if (k < 100) v = convout[((size_t)bb * TLOW + 0) * LC + (k - 80)];
                    else if (k == 100) v = interp[(size_t)bb * TT + 0];
                    else               v = gsx[(size_t)bb * TT + 0];
                }
                pf[u] = v;
            }
            #pragma unroll
            for (int u = 0; u < 5; u++) {
                int e = tid + 192 * u;
                if (e < 816) { int bb = e / 102, k = e - 102 * bb; xv[0][bb][k] = f2h_bits(pf[u]); }
            }
        }
        __syncthreads();

        for (int t = 0; t < TT; t++) {
            // prefetch x(t+1): loads fly during the poll spin
            int tn = (t + 1 < TT) ? (t + 1) : (TT - 1);
            int tmi = tn / 100, tli = tn / 10;
            float pf[5];
            #pragma unroll
            for (int u = 0; u < 5; u++) {
                int e = tid + 192 * u; float v = 0.f;
                if (e < 816) {
                    int bb = e / 102, k = e - 102 * bb;
                    if (k < 80)       v = mel[((size_t)bb * TMEL + tmi) * NMEL + k];
                    else if (k < 100) v = convout[((size_t)bb * TLOW + tli) * LC + (k - 80)];
                    else if (k == 100) v = interp[(size_t)bb * TT + tn];
                    else               v = gsx[(size_t)bb * TT + tn];
                }
                pf[u] = v;
            }

            if (wv == 0) poll_stage(h0buf + (size_t)t * 1024, lane, stH);
            __syncthreads();   // B1: stH ready

            f32x4 accX = {0.f, 0.f, 0.f, 0.f};
            #pragma unroll
            for (int kt = 0; kt < 4; kt++) {
                half8 xf = *(const half8*)&xv[t & 1][lm][kt * 32 + lk * 8];
                accX = mfma(wf[kt], xf, accX);
            }
            f32x4 a0 = {0.f, 0.f, 0.f, 0.f}, a1 = {0.f, 0.f, 0.f, 0.f};
            #pragma unroll
            for (int i = 0; i < 8; i++) a0 = mfma(wf[4 + i], ldsfrag(stH, lane, i), a0);
            #pragma unroll
            for (int i = 0; i < 8; i++) a1 = mfma(wf[12 + i], ldsfrag(stH, lane, 8 + i), a1);
            f32x4 accH = a0 + a1;

            // write next x buffer (dbuf: no extra barrier needed)
            #pragma unroll
            for (int u = 0; u < 5; u++) {
                int e = tid + 192 * u;
                if (e < 816) { int bb = e / 102, k = e - 102 * bb; xv[(t + 1) & 1][bb][k] = f2h_bits(pf[u]); }
            }
            if (lm < 8) {
                #pragma unroll
                for (int r2 = 0; r2 < 4; r2++) {
                    exch[wv][0][lk * 4 + r2][lm] = accX[r2];
                    exch[wv][1][lk * 4 + r2][lm] = accH[r2];
                }
            }
            __syncthreads();   // B2: exch ready
            if (wv == 0) {
                float Xr0 = exch[0][0][ci0][cbb], Hr0 = exch[0][1][ci0][cbb];
                float Xz0 = exch[1][0][ci0][cbb], Hz0 = exch[1][1][ci0][cbb];
                float Xn0 = exch[2][0][ci0][cbb], Hn0 = exch[2][1][ci0][cbb];
                float r0 = sigf(Xr0 + Hr0 + bi0[0] + bh0[0]);
                float z0 = sigf(Xz0 + Hz0 + bi0[1] + bh0[1]);
                float n0 = tanhf_(Xn0 + bi0[2] + r0 * (Hn0 + bh0[2]));
                hr0 = (1.f - z0) * n0 + z0 * hr0;
                float Xr1 = exch[0][0][ci1][cbb], Hr1 = exch[0][1][ci1][cbb];
                float Xz1 = exch[1][0][ci1][cbb], Hz1 = exch[1][1][ci1][cbb];
                float Xn1 = exch[2][0][ci1][cbb], Hn1 = exch[2][1][ci1][cbb];
                float r1 = sigf(Xr1 + Hr1 + bi1[0] + bh1[0]);
                float z1 = sigf(Xz1 + Hz1 + bi1[1] + bh1[1]);
                float n1 = tanhf_(Xn1 + bi1[2] + r1 * (Hn1 + bh1[2]));
                hr1 = (1.f - z1) * n1 + z1 * hr1;
                unsigned int pk = (unsigned int)f2h_bits(hr0) | ((unsigned int)f2h_bits(hr1) << 16);
                unsigned int* o32 = (unsigned int*)(h0buf + (size_t)(t + 1) * 1024)
                                  + (size_t)cbb * 256 + (cb >> 1) + (lane & 7);
                __hip_atomic_store(o32, pk, __ATOMIC_RELAXED, __HIP_MEMORY_SCOPE_AGENT);
            }
            // non-cell waves run ahead to next B1; safe (exch writes gated by B1,
            // which wv0 reaches only after cell + publish + next poll)
        }
    } else {
        // layer 1: K = [h0 | h1] concat (1024). kt 0-15 = wih1, kt 16-31 = whh1.
        half8 wf[32];
        #pragma unroll
        for (int kt = 0; kt < 32; kt++) {
            #pragma unroll
            for (int j = 0; j < 8; j++) {
                int k = kt * 32 + lk * 8 + j;
                float v = (kt < 16) ? wih1[(size_t)row * 512 + k]
                                    : whh1[(size_t)row * 512 + (k - 512)];
                wf[kt][j] = (_Float16)v;
            }
        }
        __syncthreads();

        for (int t = 0; t < TT; t++) {
            // parallel polls: wv0 stages h0[t] (slot t+1; L0 runs ahead),
            // wv1 stages h1[t-1] (slot t, the recurrence edge)
            if (wv == 0)      poll_stage(h0buf + (size_t)(t + 1) * 1024, lane, stX);
            else if (wv == 1) poll_stage(h1buf + (size_t)t * 1024,       lane, stH);
            __syncthreads();   // B1

            f32x4 x0 = {0.f, 0.f, 0.f, 0.f}, x1 = {0.f, 0.f, 0.f, 0.f};
            #pragma unroll
            for (int i = 0; i < 8; i++) x0 = mfma(wf[i],     ldsfrag(stX, lane, i),     x0);
            #pragma unroll
            for (int i = 0; i < 8; i++) x1 = mfma(wf[8 + i], ldsfrag(stX, lane, 8 + i), x1);
            f32x4 accX = x0 + x1;
            f32x4 a0 = {0.f, 0.f, 0.f, 0.f}, a1 = {0.f, 0.f, 0.f, 0.f};
            #pragma unroll
            for (int i = 0; i < 8; i++) a0 = mfma(wf[16 + i], ldsfrag(stH, lane, i),     a0);
            #pragma unroll
            for (int i = 0; i < 8; i++) a1 = mfma(wf[24 + i], ldsfrag(stH, lane, 8 + i), a1);
            f32x4 accH = a0 + a1;

            if (lm < 8) {
                #pragma unroll
                for (int r2 = 0; r2 < 4; r2++) {
                    exch[wv][0][lk * 4 + r2][lm] = accX[r2];
                    exch[wv][1][lk * 4 + r2][lm] = accH[r2];
                }
            }
            __syncthreads();   // B2
            if (wv == 0) {
                float Xr0 = exch[0][0][ci0][cbb], Hr0 = exch[0][1][ci0][cbb];
                float Xz0 = exch[1][0][ci0][cbb], Hz0 = exch[1][1][ci0][cbb];
                float Xn0 = exch[2][0][ci0][cbb], Hn0 = exch[2][1][ci0][cbb];
                float r0 = sigf(Xr0 + Hr0 + bi0[0] + bh0[0]);
                float z0 = sigf(Xz0 + Hz0 + bi0[1] + bh0[1]);
                float n0 = tanhf_(Xn0 + bi0[2] + r0 * (Hn0 + bh0[2]));
                hr0 = (1.f - z0) * n0 + z0 * hr0;
                float Xr1 = exch[0][0][ci1][cbb], Hr1 = exch[0][1][ci1][cbb];
                float Xz1 = exch[1][0][ci1][cbb], Hz1 = exch[1][1][ci1][cbb];
                float Xn1 = exch[2][0][ci1][cbb], Hn1 = exch[2][1][ci1][cbb];
                float r1 = sigf(Xr1 + Hr1 + bi1[0] + bh1[0]);
                float z1 = sigf(Xz1 + Hz1 + bi1[1] + bh1[1]);
                float n1 = tanhf_(Xn1 + bi1[2] + r1 * (Hn1 + bh1[2]));
                hr1 = (1.f - z1) * n1 + z1 * hr1;
                unsigned int pk = (unsigned int)f2h_bits(hr0) | ((unsigned int)f2h_bits(hr1) << 16);
                unsigned int* o32 = (unsigned int*)(h1buf + (size_t)(t + 1) * 1024)
                                  + (size_t)cbb * 256 + (cb >> 1) + (lane & 7);
                __hip_atomic_store(o32, pk, __ATOMIC_RELAXED, __HIP_MEMORY_SCOPE_AGENT);
            }
        }
    }
}

// ---------------- K3: fused head ----------------
__global__ __launch_bounds__(256) void k_final(
    const unsigned long long* __restrict__ h1buf,
    const unsigned short* __restrict__ prew16, const float* __restrict__ pre_b,
    const unsigned short* __restrict__ outw16, const float* __restrict__ out_b,
    float* __restrict__ out)
{
    int blk = blockIdx.x; int b = blk / 125; int tb = (blk - b * 125) * 64;
    int tid = threadIdx.x; int wv = tid >> 6; int l = tid & 63;
    int lm = l & 15, lk = l >> 4;

    half8 af[16];
    int trow = tb + wv * 16 + lm;
    const unsigned long long* abase = h1buf + ((size_t)(trow + 1) * 8 + b) * 128;
    #pragma unroll
    for (int kt = 0; kt < 16; kt++)
        af[kt] = mkfrag(abase[kt * 8 + lk * 2], abase[kt * 8 + lk * 2 + 1]);

    f32x4 acc[16];
    #pragma unroll
    for (int nt = 0; nt < 16; nt++) {
        f32x4 z = {0.f, 0.f, 0.f, 0.f}; acc[nt] = z;
        #pragma unroll
        for (int kt = 0; kt < 16; kt++) {
            int n = nt * 16 + lm; int k = kt * 32 + lk * 8;
            half8 bw = *(const half8*)&prew16[(size_t)n * HD + k];
            acc[nt] = mfma(af[kt], bw, acc[nt]);
        }
    }
    __shared__ __align__(16) unsigned short pt[64][264];
    #pragma unroll
    for (int nt = 0; nt < 16; nt++) {
        float pb = pre_b[nt * 16 + lm];
        #pragma unroll
        for (int r2 = 0; r2 < 4; r2++)
            pt[wv * 16 + lk * 4 + r2][nt * 16 + lm] = f2h_bits(tanhf_(acc[nt][r2] + pb));
    }
    __syncthreads();
    f32x4 a2[2];
    { f32x4 z = {0.f, 0.f, 0.f, 0.f}; a2[0] = z; a2[1] = z; }
    #pragma unroll
    for (int kt = 0; kt < 8; kt++) {
        half8 pa = *(const half8*)&pt[wv * 16 + lm][kt * 32 + lk * 8];
        #pragma unroll
        for (int nt = 0; nt < 2; nt++) {
            int n = nt * 16 + lm;
            half8 bw = (n < NSS) ? *(const half8*)&outw16[(size_t)n * NPRE + kt * 32 + lk * 8]
                                 : mkfrag(0ull, 0ull);
            a2[nt] = mfma(pa, bw, a2[nt]);
        }
    }
    #pragma unroll
    for (int nt = 0; nt < 2; nt++) {
        int n = nt * 16 + lm;
        if (n < NSS) {
            float ob = out_b[n];
            #pragma unroll
            for (int r2 = 0; r2 < 4; r2++) {
                int t = tb + wv * 16 + lk * 4 + r2;
                out[((size_t)b * TT + t) * NSS + n] = a2[nt][r2] + ob;
            }
        }
    }
}

// ---------------- launch ----------------
extern "C" void kernel_launch(void* const* d_in, const int* in_sizes, int n_in,
                              void* d_out, int out_size, void* d_ws, size_t ws_size,
                              hipStream_t stream) {
    const float* mel  = (const float*)d_in[0];
    const float* xlow = (const float*)d_in[1];
    const float* gsx  = (const float*)d_in[2];
    const float* cw0  = (const float*)d_in[3];
    const float* cb0  = (const float*)d_in[4];
    const float* cw1  = (const float*)d_in[5];
    const float* cb1  = (const float*)d_in[6];
    const float* cw2  = (const float*)d_in[7];
    const float* cb2  = (const float*)d_in[8];
    const float* wih0 = (const float*)d_in[9];
    const float* whh0 = (const float*)d_in[10];
    const float* bih0 = (const float*)d_in[11];
    const float* bhh0 = (const float*)d_in[12];
    const float* wih1 = (const float*)d_in[13];
    const float* whh1 = (const float*)d_in[14];
    const float* bih1 = (const float*)d_in[15];
    const float* bhh1 = (const float*)d_in[16];
    const float* prew = (const float*)d_in[17];
    const float* preb = (const float*)d_in[18];
    const float* outw = (const float*)d_in[19];
    const float* outb = (const float*)d_in[20];

    size_t needed = 2 * HB_BYTES + CONV_BYTES + INTERP_BYTES + PREW16_BYTES + OUTW16_BYTES;
    if (ws_size < needed) return;

    char* ws = (char*)d_ws;
    unsigned long long* h0buf = (unsigned long long*)ws;
    unsigned long long* h1buf = (unsigned long long*)(ws + HB_BYTES);
    float* convout = (float*)(ws + 2 * HB_BYTES);
    float* interp  = (float*)(ws + 2 * HB_BYTES + CONV_BYTES);
    unsigned short* prew16 = (unsigned short*)(ws + 2 * HB_BYTES + CONV_BYTES + INTERP_BYTES);
    unsigned short* outw16 = (unsigned short*)(ws + 2 * HB_BYTES + CONV_BYTES + INTERP_BYTES + PREW16_BYTES);

    // sentinel-init both h broadcast buffers (0xFF.. = NaN fp16 pairs / 0xFFFFFFFF u32 sentinel)
    hipMemsetAsync(ws, 0xFF, 2 * HB_BYTES, stream);

    k_prep<<<(NPRE * HD + 255) / 256, 256, 0, stream>>>(prew, outw, prew16, outw16);
    k_conv<<<32, 256, 0, stream>>>(xlow, cw0, cb0, cw1, cb1, cw2, cb2, convout, interp);
    k_rnn<<<64, 192, 0, stream>>>(mel, gsx, convout, interp,
                                  wih0, whh0, bih0, bhh0,
                                  wih1, whh1, bih1, bhh1,
                                  h0buf, h1buf);
    k_final<<<1000, 256, 0, stream>>>(h1buf, prew16, preb, outw16, outb, (float*)d_out);
}

// Round 9
// 21182.423 us; speedup vs baseline: 2.5485x; 1.1094x over previous
//
#include <hip/hip_runtime.h>
#include <hip/hip_fp16.h>
#include <stdint.h>

// ---------------- problem constants ----------------
#define TT     8000
#define TLOW   800
#define TMEL   80
#define NMEL   80
#define NB     8
#define HD     512
#define LC     20
#define NPRE   256
#define NSS    30

// h broadcast buffers: slot s holds h[s-1]; slot 0 = zeros. per slot: 8 batches x 128 u64 (512 fp16)
#define HB_SLOTS (TT + 1)
#define HB_U64   ((size_t)HB_SLOTS * 8 * 128)
#define HB_BYTES (HB_U64 * 8)
#define CONV_BYTES   ((size_t)NB * TLOW * LC * 4)
#define INTERP_BYTES ((size_t)NB * TT * 4)
#define PREW16_BYTES ((size_t)NPRE * HD * 2)
#define OUTW16_BYTES ((size_t)NSS * NPRE * 2)

typedef __attribute__((ext_vector_type(8))) _Float16 half8;
typedef __attribute__((ext_vector_type(4))) float f32x4;

static __device__ __forceinline__ unsigned short f2h_bits(float f) {
    union { _Float16 h; unsigned short u; } c; c.h = (_Float16)f; return c.u;  // RNE
}
static __device__ __forceinline__ float sigf(float x) {
    x = fminf(30.f, fmaxf(-30.f, x));
    return 1.f / (1.f + __expf(-x));
}
static __device__ __forceinline__ float tanhf_(float x) {
    x = fminf(15.f, fmaxf(-15.f, x));
    float e = __expf(2.f * x);
    return (e - 1.f) / (e + 1.f);
}
static __device__ __forceinline__ half8 mkfrag(unsigned long long a, unsigned long long b) {
    union { unsigned long long q[2]; half8 v; } u; u.q[0] = a; u.q[1] = b; return u.v;
}
static __device__ __forceinline__ f32x4 mfma(half8 a, half8 b, f32x4 c) {
    return __builtin_amdgcn_mfma_f32_16x16x32_f16(a, b, c, 0, 0, 0);
}

// ---------------- poll primitives ----------------
// Data-carrying polls: the load batch that detects readiness IS the data
// (round-8 lesson: separating detect from data adds a serial RT).
static __device__ __forceinline__ void issue16(const unsigned long long* __restrict__ p,
                                               int lane, unsigned long long* __restrict__ q)
{
    #pragma unroll
    for (int k = 0; k < 16; k++)
        q[k] = __hip_atomic_load(p + lane + 64 * k, __ATOMIC_RELAXED, __HIP_MEMORY_SCOPE_AGENT);
}
static __device__ __forceinline__ bool good16(const unsigned long long* __restrict__ q)
{
    bool bad = false;
    #pragma unroll
    for (int k = 0; k < 16; k++) {
        unsigned int lo = (unsigned int)q[k], hi = (unsigned int)(q[k] >> 32);
        bad |= (lo == 0xFFFFFFFFu) | (hi == 0xFFFFFFFFu);
    }
    return !__any(bad);
}
static __device__ __forceinline__ void stage16(unsigned long long* __restrict__ st,
                                               int lane, const unsigned long long* __restrict__ q)
{
    #pragma unroll
    for (int k = 0; k < 16; k++) { int i = lane + 64 * k; st[(i >> 7) * 129 + (i & 127)] = q[k]; }
}
// 2-deep pipelined hot poll (critical edge): two batches in flight; sampling
// period ~ issue+check instead of a full load RT.
static __device__ void poll_hot(const unsigned long long* __restrict__ slot,
                                int lane, unsigned long long* __restrict__ st)
{
    unsigned long long a[16], b[16];
    issue16(slot, lane, a);
    issue16(slot, lane, b);
    for (;;) {
        if (good16(a)) { stage16(st, lane, a); return; }
        issue16(slot, lane, a);
        if (good16(b)) { stage16(st, lane, b); return; }
        issue16(slot, lane, b);
    }
}
// sleepy poll (off-critical-path prefetch source)
static __device__ void poll_sleep(const unsigned long long* __restrict__ slot,
                                  int lane, unsigned long long* __restrict__ st)
{
    unsigned long long a[16];
    for (;;) {
        issue16(slot, lane, a);
        if (good16(a)) break;
        __builtin_amdgcn_s_sleep(1);
    }
    stage16(st, lane, a);
}
// frag read from staged slot: batch = lane&7 (cols 8-15 mirror, discarded on write)
static __device__ __forceinline__ half8 ldsfrag(const unsigned long long* __restrict__ st,
                                                int lane, int kt)
{
    int base = (lane & 7) * 129 + ((lane >> 4) << 1) + kt * 8;
    return mkfrag(st[base], st[base + 1]);
}

// ---------------- K0: convert pre_w / out_w to fp16 ----------------
__global__ __launch_bounds__(256) void k_prep(
    const float* __restrict__ pre_w, const float* __restrict__ out_w,
    unsigned short* __restrict__ prew16, unsigned short* __restrict__ outw16)
{
    int i = blockIdx.x * 256 + threadIdx.x;
    if (i < NPRE * HD) prew16[i] = f2h_bits(pre_w[i]);
    if (i < NSS * NPRE) outw16[i] = f2h_bits(out_w[i]);
}

// ---------------- K1: conv stack + linear interp (all f32) ----------------
#define CHW 218   // 200 + 2*9 halo (3 conv layers x pad 3)
__global__ __launch_bounds__(256) void k_conv(
    const float* __restrict__ xlow,
    const float* __restrict__ w0, const float* __restrict__ cb0,
    const float* __restrict__ w1, const float* __restrict__ cb1,
    const float* __restrict__ w2, const float* __restrict__ cb2,
    float* __restrict__ convout, float* __restrict__ interp)
{
    int blk = blockIdx.x; int b = blk >> 2; int ch = blk & 3; int cb = ch * 200;
    int tid = threadIdx.x;
    __shared__ float xr[224];
    __shared__ float w0l[LC * 7], w1l[LC * LC * 7], w2l[LC * LC * 7];
    __shared__ float b0l[LC], b1l[LC], b2l[LC];
    __shared__ float h0[LC][CHW], h1[LC][CHW];

    for (int i = tid; i < LC * 7; i += 256) w0l[i] = w0[i];
    for (int i = tid; i < LC * LC * 7; i += 256) { w1l[i] = w1[i]; w2l[i] = w2[i]; }
    for (int i = tid; i < LC; i += 256) { b0l[i] = cb0[i]; b1l[i] = cb1[i]; b2l[i] = cb2[i]; }
    for (int i = tid; i < 224; i += 256) {
        int g = cb - 12 + i;
        xr[i] = (g >= 0 && g < TLOW) ? xlow[b * TLOW + g] : 0.f;
    }
    __syncthreads();
    for (int i = tid; i < LC * CHW; i += 256) {
        int c = i / CHW, s = i - c * CHW;
        int tg = cb - 9 + s;
        float a = b0l[c];
        #pragma unroll
        for (int j = 0; j < 7; j++) a += w0l[c * 7 + j] * xr[s + j];
        h0[c][s] = (tg >= 0 && tg < TLOW) ? tanhf_(a) : 0.f;
    }
    __syncthreads();
    for (int i = tid; i < LC * CHW; i += 256) {
        int c = i / CHW, s = i - c * CHW;
        int tg = cb - 9 + s;
        float a = b1l[c];
        for (int ci = 0; ci < LC; ci++) {
            #pragma unroll
            for (int j = 0; j < 7; j++) {
                int ss = s + j - 3;
                float hv = (ss >= 0 && ss < CHW) ? h0[ci][ss] : 0.f;
                a += w1l[(c * LC + ci) * 7 + j] * hv;
            }
        }
        h1[c][s] = (tg >= 0 && tg < TLOW) ? tanhf_(a) : 0.f;
    }
    __syncthreads();
    for (int i = tid; i < LC * 200; i += 256) {
        int c = i / 200, t0 = i - c * 200; int s = t0 + 9;
        float a = b2l[c];
        for (int ci = 0; ci < LC; ci++) {
            #pragma unroll
            for (int j = 0; j < 7; j++) a += w2l[(c * LC + ci) * 7 + j] * h1[ci][s + j - 3];
        }
        convout[((size_t)b * TLOW + cb + t0) * LC + c] = tanhf_(a);
    }
    for (int i = tid; i < 2000; i += 256) {
        int t = cb * 10 + i;
        float src = ((float)t + 0.5f) * 0.1f - 0.5f;
        src = fminf(fmaxf(src, 0.f), (float)(TLOW - 1));
        int i0 = (int)floorf(src); int i1 = (i0 + 1 < TLOW) ? i0 + 1 : TLOW - 1;
        float w = src - (float)i0;
        interp[(size_t)b * TT + t] = xlow[b * TLOW + i0] * (1.f - w) + xlow[b * TLOW + i1] * w;
    }
}

// ---------------- K2: persistent GRU recurrence ----------------
// grid: 64 blocks x 384 threads (6 waves = 3 gates x {X,H}).
// blocks 0-31 = layer0 chunks (16 h each), 32-63 = layer1 chunks.
// Wave roles: g = wv>>1 (gate), isH = wv&1 (x-part vs h-part matvec).
// Pollers: L0 wave1 (hot, h0 edge); L1 wave0 (sleepy, h0 prefetch) + wave1 (hot, h1 edge).
__global__ __launch_bounds__(384, 1) void k_rnn(
    const float* __restrict__ mel, const float* __restrict__ gsx,
    const float* __restrict__ convout, const float* __restrict__ interp,
    const float* __restrict__ wih0, const float* __restrict__ whh0,
    const float* __restrict__ bih0, const float* __restrict__ bhh0,
    const float* __restrict__ wih1, const float* __restrict__ whh1,
    const float* __restrict__ bih1, const float* __restrict__ bhh1,
    unsigned long long* __restrict__ h0buf, unsigned long long* __restrict__ h1buf)
{
    const int tid = threadIdx.x;
    const int wv = tid >> 6;          // 0..5
    const int lane = tid & 63;
    const int lm = lane & 15, lk = lane >> 4;
    const int g = wv >> 1;            // gate (r,z,n)
    const int isH = wv & 1;           // 0 = x-part, 1 = h-part
    const bool isL0 = (blockIdx.x < 32);
    const int cbid = isL0 ? blockIdx.x : (blockIdx.x - 32);
    const int cb = cbid * 16;                  // h-index chunk base
    const int row = g * 512 + cb + lm;         // gate weight row for this lane

    __shared__ float exch[3][2][16][9];        // [gate][x/h][row][batch(pad 9)]
    __shared__ __align__(16) unsigned short xv[2][16][136];  // L0 input, double-buffered
    __shared__ unsigned long long stX[8 * 129]; // staged h0 slot (L1 x-part)
    __shared__ unsigned long long stH[8 * 129]; // staged edge slot (L0: h0; L1: h1)

    // cell lanes (wv0, 64 lanes): batch bb = lane>>3, rows i0=2*(lane&7), i1=i0+1
    const int cbb = lane >> 3;
    const int ci0 = (lane & 7) * 2, ci1 = ci0 + 1;
    float hr0 = 0.f, hr1 = 0.f;                // f32 recurrence state (registers)
    float bi0[3], bi1[3], bh0[3], bh1[3];
    if (wv == 0) {
        const float* bi = isL0 ? bih0 : bih1;
        const float* bh = isL0 ? bhh0 : bhh1;
        #pragma unroll
        for (int gg = 0; gg < 3; gg++) {
            bi0[gg] = bi[gg * 512 + cb + ci0]; bi1[gg] = bi[gg * 512 + cb + ci1];
            bh0[gg] = bh[gg * 512 + cb + ci0]; bh1[gg] = bh[gg * 512 + cb + ci1];
        }
    }
    for (int i = tid; i < 2 * 16 * 136; i += 384) (&xv[0][0][0])[i] = 0;

    // publish h[-1] = 0 for own chunk (slot 0): 64 u32 stores by wv0
    if (wv == 0) {
        unsigned long long* buf = isL0 ? h0buf : h1buf;
        unsigned int* o32 = (unsigned int*)buf + (size_t)cbb * 256 + (cb >> 1) + (lane & 7);
        __hip_atomic_store(o32, 0u, __ATOMIC_RELAXED, __HIP_MEMORY_SCOPE_AGENT);
    }

    // weights resident in VGPRs: 16 half8 = 64 VGPR per wave
    half8 wf[16];
    if (isL0) {
        if (!isH) {
            #pragma unroll
            for (int kt = 0; kt < 4; kt++)
                #pragma unroll
                for (int j = 0; j < 8; j++) {
                    int k = kt * 32 + lk * 8 + j;
                    wf[kt][j] = (k < 102) ? (_Float16)wih0[(size_t)row * 102 + k] : (_Float16)0.f;
                }
        } else {
            #pragma unroll
            for (int kt = 0; kt < 16; kt++)
                #pragma unroll
                for (int j = 0; j < 8; j++)
                    wf[kt][j] = (_Float16)whh0[(size_t)row * 512 + kt * 32 + lk * 8 + j];
        }
    } else {
        const float* wsrc = isH ? whh1 : wih1;
        #pragma unroll
        for (int kt = 0; kt < 16; kt++)
            #pragma unroll
            for (int j = 0; j < 8; j++)
                wf[kt][j] = (_Float16)wsrc[(size_t)row * 512 + kt * 32 + lk * 8 + j];
    }

    if (isL0) {
        // initial xv[0] = x(0)
        {
            float pf[3];
            #pragma unroll
            for (int u = 0; u < 3; u++) {
                int e = tid + 384 * u; float v = 0.f;
                if (e < 816) {
                    int bb = e / 102, k = e - 102 * bb;
                    if (k < 80)       v = mel[((size_t)bb * TMEL + 0) * NMEL + k];
                    else if (k < 100) v = convout[((size_t)bb * TLOW + 0) * LC + (k - 80)];
                    else if (k == 100) v = interp[(size_t)bb * TT + 0];
                    else               v = gsx[(size_t)bb * TT + 0];
                }
                pf[u] = v;
            }
            #pragma unroll
            for (int u = 0; u < 3; u++) {
                int e = tid + 384 * u;
                if (e < 816) { int bb = e / 102, k = e - 102 * bb; xv[0][bb][k] = f2h_bits(pf[u]); }
            }
        }
        __syncthreads();

        for (int t = 0; t < TT; t++) {
            // prefetch x(t+1): loads fly during the poll spin
            int tn = (t + 1 < TT) ? (t + 1) : (TT - 1);
            int tmi = tn / 100, tli = tn / 10;
            float pf[3];
            #pragma unroll
            for (int u = 0; u < 3; u++) {
                int e = tid + 384 * u; float v = 0.f;
                if (e < 816) {
                    int bb = e / 102, k = e - 102 * bb;
                    if (k < 80)       v = mel[((size_t)bb * TMEL + tmi) * NMEL + k];
                    else if (k < 100) v = convout[((size_t)bb * TLOW + tli) * LC + (k - 80)];
                    else if (k == 100) v = interp[(size_t)bb * TT + tn];
                    else               v = gsx[(size_t)bb * TT + tn];
                }
                pf[u] = v;
            }

            if (wv == 1) poll_hot(h0buf + (size_t)t * 1024, lane, stH);
            __syncthreads();   // B1: stH ready

            if (!isH) {
                f32x4 acc = {0.f, 0.f, 0.f, 0.f};
                #pragma unroll
                for (int kt = 0; kt < 4; kt++) {
                    half8 xf = *(const half8*)&xv[t & 1][lm][kt * 32 + lk * 8];
                    acc = mfma(wf[kt], xf, acc);
                }
                if (lm < 8) {
                    #pragma unroll
                    for (int r2 = 0; r2 < 4; r2++) exch[g][0][lk * 4 + r2][lm] = acc[r2];
                }
            } else {
                f32x4 a0 = {0.f, 0.f, 0.f, 0.f}, a1 = {0.f, 0.f, 0.f, 0.f};
                #pragma unroll
                for (int i = 0; i < 8; i++) a0 = mfma(wf[i], ldsfrag(stH, lane, i), a0);
                #pragma unroll
                for (int i = 0; i < 8; i++) a1 = mfma(wf[8 + i], ldsfrag(stH, lane, 8 + i), a1);
                f32x4 acc = a0 + a1;
                if (lm < 8) {
                    #pragma unroll
                    for (int r2 = 0; r2 < 4; r2++) exch[g][1][lk * 4 + r2][lm] = acc[r2];
                }
            }
            // write next x buffer (dbuf: no extra barrier needed)
            #pragma unroll
            for (int u = 0; u < 3; u++) {
                int e = tid + 384 * u;
                if (e < 816) { int bb = e / 102, k = e - 102 * bb; xv[(t + 1) & 1][bb][k] = f2h_bits(pf[u]); }
            }
            __syncthreads();   // B2: exch ready
            if (wv == 0) {
                float r0 = sigf(exch[0][0][ci0][cbb] + exch[0][1][ci0][cbb] + bi0[0] + bh0[0]);
                float z0 = sigf(exch[1][0][ci0][cbb] + exch[1][1][ci0][cbb] + bi0[1] + bh0[1]);
                float n0 = tanhf_(exch[2][0][ci0][cbb] + bi0[2] + r0 * (exch[2][1][ci0][cbb] + bh0[2]));
                hr0 = (1.f - z0) * n0 + z0 * hr0;
                float r1 = sigf(exch[0][0][ci1][cbb] + exch[0][1][ci1][cbb] + bi1[0] + bh1[0]);
                float z1 = sigf(exch[1][0][ci1][cbb] + exch[1][1][ci1][cbb] + bi1[1] + bh1[1]);
                float n1 = tanhf_(exch[2][0][ci1][cbb] + bi1[2] + r1 * (exch[2][1][ci1][cbb] + bh1[2]));
                hr1 = (1.f - z1) * n1 + z1 * hr1;
                unsigned int pk = (unsigned int)f2h_bits(hr0) | ((unsigned int)f2h_bits(hr1) << 16);
                unsigned int* o32 = (unsigned int*)(h0buf + (size_t)(t + 1) * 1024)
                                  + (size_t)cbb * 256 + (cb >> 1) + (lane & 7);
                __hip_atomic_store(o32, pk, __ATOMIC_RELAXED, __HIP_MEMORY_SCOPE_AGENT);
            }
        }
    } else {
        __syncthreads();
        for (int t = 0; t < TT; t++) {
            // parallel polls: wv0 (sleepy) stages h0[t] (slot t+1; L0 runs ahead),
            // wv1 (hot, 2-deep) stages h1[t-1] (slot t, the recurrence edge)
            if (wv == 0)      poll_sleep(h0buf + (size_t)(t + 1) * 1024, lane, stX);
            else if (wv == 1) poll_hot(h1buf + (size_t)t * 1024, lane, stH);
            __syncthreads();   // B1

            const unsigned long long* src = isH ? stH : stX;
            f32x4 a0 = {0.f, 0.f, 0.f, 0.f}, a1 = {0.f, 0.f, 0.f, 0.f};
            #pragma unroll
            for (int i = 0; i < 8; i++) a0 = mfma(wf[i], ldsfrag(src, lane, i), a0);
            #pragma unroll
            for (int i = 0; i < 8; i++) a1 = mfma(wf[8 + i], ldsfrag(src, lane, 8 + i), a1);
            f32x4 acc = a0 + a1;
            if (lm < 8) {
                #pragma unroll
                for (int r2 = 0; r2 < 4; r2++) exch[g][isH][lk * 4 + r2][lm] = acc[r2];
            }
            __syncthreads();   // B2
            if (wv == 0) {
                float r0 = sigf(exch[0][0][ci0][cbb] + exch[0][1][ci0][cbb] + bi0[0] + bh0[0]);
                float z0 = sigf(exch[1][0][ci0][cbb] + exch[1][1][ci0][cbb] + bi0[1] + bh0[1]);
                float n0 = tanhf_(exch[2][0][ci0][cbb] + bi0[2] + r0 * (exch[2][1][ci0][cbb] + bh0[2]));
                hr0 = (1.f - z0) * n0 + z0 * hr0;
                float r1 = sigf(exch[0][0][ci1][cbb] + exch[0][1][ci1][cbb] + bi1[0] + bh1[0]);
                float z1 = sigf(exch[1][0][ci1][cbb] + exch[1][1][ci1][cbb] + bi1[1] + bh1[1]);
                float n1 = tanhf_(exch[2][0][ci1][cbb] + bi1[2] + r1 * (exch[2][1][ci1][cbb] + bh1[2]));
                hr1 = (1.f - z1) * n1 + z1 * hr1;
                unsigned int pk = (unsigned int)f2h_bits(hr0) | ((unsigned int)f2h_bits(hr1) << 16);
                unsigned int* o32 = (unsigned int*)(h1buf + (size_t)(t + 1) * 1024)
                                  + (size_t)cbb * 256 + (cb >> 1) + (lane & 7);
                __hip_atomic_store(o32, pk, __ATOMIC_RELAXED, __HIP_MEMORY_SCOPE_AGENT);
            }
        }
    }
}

// ---------------- K3: fused head ----------------
__global__ __launch_bounds__(256) void k_final(
    const unsigned long long* __restrict__ h1buf,
    const unsigned short* __restrict__ prew16, const float* __restrict__ pre_b,
    const unsigned short* __restrict__ outw16, const float* __restrict__ out_b,
    float* __restrict__ out)
{
    int blk = blockIdx.x; int b = blk / 125; int tb = (blk - b * 125) * 64;
    int tid = threadIdx.x; int wv = tid >> 6; int l = tid & 63;
    int lm = l & 15, lk = l >> 4;

    half8 af[16];
    int trow = tb + wv * 16 + lm;
    const unsigned long long* abase = h1buf + ((size_t)(trow + 1) * 8 + b) * 128;
    #pragma unroll
    for (int kt = 0; kt < 16; kt++)
        af[kt] = mkfrag(abase[kt * 8 + lk * 2], abase[kt * 8 + lk * 2 + 1]);

    f32x4 acc[16];
    #pragma unroll
    for (int nt = 0; nt < 16; nt++) {
        f32x4 z = {0.f, 0.f, 0.f, 0.f}; acc[nt] = z;
        #pragma unroll
        for (int kt = 0; kt < 16; kt++) {
            int n = nt * 16 + lm; int k = kt * 32 + lk * 8;
            half8 bw = *(const half8*)&prew16[(size_t)n * HD + k];
            acc[nt] = mfma(af[kt], bw, acc[nt]);
        }
    }
    __shared__ __align__(16) unsigned short pt[64][264];
    #pragma unroll
    for (int nt = 0; nt < 16; nt++) {
        float pb = pre_b[nt * 16 + lm];
        #pragma unroll
        for (int r2 = 0; r2 < 4; r2++)
            pt[wv * 16 + lk * 4 + r2][nt * 16 + lm] = f2h_bits(tanhf_(acc[nt][r2] + pb));
    }
    __syncthreads();
    f32x4 a2[2];
    { f32x4 z = {0.f, 0.f, 0.f, 0.f}; a2[0] = z; a2[1] = z; }
    #pragma unroll
    for (int kt = 0; kt < 8; kt++) {
        half8 pa = *(const half8*)&pt[wv * 16 + lm][kt * 32 + lk * 8];
        #pragma unroll
        for (int nt = 0; nt < 2; nt++) {
            int n = nt * 16 + lm;
            half8 bw = (n < NSS) ? *(const half8*)&outw16[(size_t)n * NPRE + kt * 32 + lk * 8]
                                 : mkfrag(0ull, 0ull);
            a2[nt] = mfma(pa, bw, a2[nt]);
        }
    }
    #pragma unroll
    for (int nt = 0; nt < 2; nt++) {
        int n = nt * 16 + lm;
        if (n < NSS) {
            float ob = out_b[n];
            #pragma unroll
            for (int r2 = 0; r2 < 4; r2++) {
                int t = tb + wv * 16 + lk * 4 + r2;
                out[((size_t)b * TT + t) * NSS + n] = a2[nt][r2] + ob;
            }
        }
    }
}

// ---------------- launch ----------------
extern "C" void kernel_launch(void* const* d_in, const int* in_sizes, int n_in,
                              void* d_out, int out_size, void* d_ws, size_t ws_size,
                              hipStream_t stream) {
    const float* mel  = (const float*)d_in[0];
    const float* xlow = (const float*)d_in[1];
    const float* gsx  = (const float*)d_in[2];
    const float* cw0  = (const float*)d_in[3];
    const float* cb0  = (const float*)d_in[4];
    const float* cw1  = (const float*)d_in[5];
    const float* cb1  = (const float*)d_in[6];
    const float* cw2  = (const float*)d_in[7];
    const float* cb2  = (const float*)d_in[8];
    const float* wih0 = (const float*)d_in[9];
    const float* whh0 = (const float*)d_in[10];
    const float* bih0 = (const float*)d_in[11];
    const float* bhh0 = (const float*)d_in[12];
    const float* wih1 = (const float*)d_in[13];
    const float* whh1 = (const float*)d_in[14];
    const float* bih1 = (const float*)d_in[15];
    const float* bhh1 = (const float*)d_in[16];
    const float* prew = (const float*)d_in[17];
    const float* preb = (const float*)d_in[18];
    const float* outw = (const float*)d_in[19];
    const float* outb = (const float*)d_in[20];

    size_t needed = 2 * HB_BYTES + CONV_BYTES + INTERP_BYTES + PREW16_BYTES + OUTW16_BYTES;
    if (ws_size < needed) return;

    char* ws = (char*)d_ws;
    unsigned long long* h0buf = (unsigned long long*)ws;
    unsigned long long* h1buf = (unsigned long long*)(ws + HB_BYTES);
    float* convout = (float*)(ws + 2 * HB_BYTES);
    float* interp  = (float*)(ws + 2 * HB_BYTES + CONV_BYTES);
    unsigned short* prew16 = (unsigned short*)(ws + 2 * HB_BYTES + CONV_BYTES + INTERP_BYTES);
    unsigned short* outw16 = (unsigned short*)(ws + 2 * HB_BYTES + CONV_BYTES + INTERP_BYTES + PREW16_BYTES);

    // sentinel-init both h broadcast buffers (0xFF.. = NaN fp16 pairs / 0xFFFFFFFF u32 sentinel)
    hipMemsetAsync(ws, 0xFF, 2 * HB_BYTES, stream);

    k_prep<<<(NPRE * HD + 255) / 256, 256, 0, stream>>>(prew, outw, prew16, outw16);
    k_conv<<<32, 256, 0, stream>>>(xlow, cw0, cb0, cw1, cb1, cw2, cb2, convout, interp);
    k_rnn<<<64, 384, 0, stream>>>(mel, gsx, convout, interp,
                                  wih0, whh0, bih0, bhh0,
                                  wih1, whh1, bih1, bhh1,
                                  h0buf, h1buf);
    k_final<<<1000, 256, 0, stream>>>(h1buf, prew16, preb, outw16, outb, (float*)d_out);
}

// Round 10
// 20977.068 us; speedup vs baseline: 2.5735x; 1.0098x over previous
//
#include <hip/hip_runtime.h>
#include <hip/hip_fp16.h>
#include <stdint.h>

// ---------------- problem constants ----------------
#define TT     8000
#define TLOW   800
#define TMEL   80
#define NMEL   80
#define NB     8
#define HD     512
#define LC     20
#define NPRE   256
#define NSS    30

// h broadcast buffers: slot s holds h[s-1]; slot 0 = zeros. per slot: 8 batches x 128 u64 (512 fp16)
#define HB_SLOTS (TT + 1)
#define HB_U64   ((size_t)HB_SLOTS * 8 * 128)
#define HB_BYTES (HB_U64 * 8)
#define CONV_BYTES   ((size_t)NB * TLOW * LC * 4)
#define INTERP_BYTES ((size_t)NB * TT * 4)
#define PREW16_BYTES ((size_t)NPRE * HD * 2)
#define OUTW16_BYTES ((size_t)NSS * NPRE * 2)

typedef __attribute__((ext_vector_type(8))) _Float16 half8;
typedef __attribute__((ext_vector_type(4))) float f32x4;

static __device__ __forceinline__ unsigned short f2h_bits(float f) {
    union { _Float16 h; unsigned short u; } c; c.h = (_Float16)f; return c.u;  // RNE
}
static __device__ __forceinline__ float sigf(float x) {
    x = fminf(30.f, fmaxf(-30.f, x));
    return 1.f / (1.f + __expf(-x));
}
static __device__ __forceinline__ float tanhf_(float x) {
    x = fminf(15.f, fmaxf(-15.f, x));
    float e = __expf(2.f * x);
    return (e - 1.f) / (e + 1.f);
}
static __device__ __forceinline__ half8 mkfrag(unsigned long long a, unsigned long long b) {
    union { unsigned long long q[2]; half8 v; } u; u.q[0] = a; u.q[1] = b; return u.v;
}
static __device__ __forceinline__ f32x4 mfma(half8 a, half8 b, f32x4 c) {
    return __builtin_amdgcn_mfma_f32_16x16x32_f16(a, b, c, 0, 0, 0);
}

// ---------------- single-wave data-carrying poll + LDS stage (round-6 proven) ----
static __device__ __forceinline__ void issue16(const unsigned long long* __restrict__ p,
                                               int lane, unsigned long long* __restrict__ q)
{
    #pragma unroll
    for (int k = 0; k < 16; k++)
        q[k] = __hip_atomic_load(p + lane + 64 * k, __ATOMIC_RELAXED, __HIP_MEMORY_SCOPE_AGENT);
}
static __device__ __forceinline__ bool good16(const unsigned long long* __restrict__ q)
{
    bool bad = false;
    #pragma unroll
    for (int k = 0; k < 16; k++) {
        unsigned int lo = (unsigned int)q[k], hi = (unsigned int)(q[k] >> 32);
        bad |= (lo == 0xFFFFFFFFu) | (hi == 0xFFFFFFFFu);
    }
    return !__any(bad);
}
static __device__ void poll_stage(const unsigned long long* __restrict__ slot,
                                  int lane, unsigned long long* __restrict__ st)
{
    unsigned long long q[16];
    for (;;) {
        issue16(slot, lane, q);
        if (good16(q)) break;
        __builtin_amdgcn_s_sleep(1);
    }
    #pragma unroll
    for (int k = 0; k < 16; k++) { int i = lane + 64 * k; st[(i >> 7) * 129 + (i & 127)] = q[k]; }
}
// frag read from staged slot: batch = lane&7 (cols 8-15 mirror, discarded on write)
static __device__ __forceinline__ half8 ldsfrag(const unsigned long long* __restrict__ st,
                                                int lane, int kt)
{
    int base = (lane & 7) * 129 + ((lane >> 4) << 1) + kt * 8;
    return mkfrag(st[base], st[base + 1]);
}

// ---------------- K0: convert pre_w / out_w to fp16 ----------------
__global__ __launch_bounds__(256) void k_prep(
    const float* __restrict__ pre_w, const float* __restrict__ out_w,
    unsigned short* __restrict__ prew16, unsigned short* __restrict__ outw16)
{
    int i = blockIdx.x * 256 + threadIdx.x;
    if (i < NPRE * HD) prew16[i] = f2h_bits(pre_w[i]);
    if (i < NSS * NPRE) outw16[i] = f2h_bits(out_w[i]);
}

// ---------------- K1: conv stack + linear interp (all f32) ----------------
#define CHW 218   // 200 + 2*9 halo (3 conv layers x pad 3)
__global__ __launch_bounds__(256) void k_conv(
    const float* __restrict__ xlow,
    const float* __restrict__ w0, const float* __restrict__ cb0,
    const float* __restrict__ w1, const float* __restrict__ cb1,
    const float* __restrict__ w2, const float* __restrict__ cb2,
    float* __restrict__ convout, float* __restrict__ interp)
{
    int blk = blockIdx.x; int b = blk >> 2; int ch = blk & 3; int cb = ch * 200;
    int tid = threadIdx.x;
    __shared__ float xr[224];
    __shared__ float w0l[LC * 7], w1l[LC * LC * 7], w2l[LC * LC * 7];
    __shared__ float b0l[LC], b1l[LC], b2l[LC];
    __shared__ float h0[LC][CHW], h1[LC][CHW];

    for (int i = tid; i < LC * 7; i += 256) w0l[i] = w0[i];
    for (int i = tid; i < LC * LC * 7; i += 256) { w1l[i] = w1[i]; w2l[i] = w2[i]; }
    for (int i = tid; i < LC; i += 256) { b0l[i] = cb0[i]; b1l[i] = cb1[i]; b2l[i] = cb2[i]; }
    for (int i = tid; i < 224; i += 256) {
        int g = cb - 12 + i;
        xr[i] = (g >= 0 && g < TLOW) ? xlow[b * TLOW + g] : 0.f;
    }
    __syncthreads();
    for (int i = tid; i < LC * CHW; i += 256) {
        int c = i / CHW, s = i - c * CHW;
        int tg = cb - 9 + s;
        float a = b0l[c];
        #pragma unroll
        for (int j = 0; j < 7; j++) a += w0l[c * 7 + j] * xr[s + j];
        h0[c][s] = (tg >= 0 && tg < TLOW) ? tanhf_(a) : 0.f;
    }
    __syncthreads();
    for (int i = tid; i < LC * CHW; i += 256) {
        int c = i / CHW, s = i - c * CHW;
        int tg = cb - 9 + s;
        float a = b1l[c];
        for (int ci = 0; ci < LC; ci++) {
            #pragma unroll
            for (int j = 0; j < 7; j++) {
                int ss = s + j - 3;
                float hv = (ss >= 0 && ss < CHW) ? h0[ci][ss] : 0.f;
                a += w1l[(c * LC + ci) * 7 + j] * hv;
            }
        }
        h1[c][s] = (tg >= 0 && tg < TLOW) ? tanhf_(a) : 0.f;
    }
    __syncthreads();
    for (int i = tid; i < LC * 200; i += 256) {
        int c = i / 200, t0 = i - c * 200; int s = t0 + 9;
        float a = b2l[c];
        for (int ci = 0; ci < LC; ci++) {
            #pragma unroll
            for (int j = 0; j < 7; j++) a += w2l[(c * LC + ci) * 7 + j] * h1[ci][s + j - 3];
        }
        convout[((size_t)b * TLOW + cb + t0) * LC + c] = tanhf_(a);
    }
    for (int i = tid; i < 2000; i += 256) {
        int t = cb * 10 + i;
        float src = ((float)t + 0.5f) * 0.1f - 0.5f;
        src = fminf(fmaxf(src, 0.f), (float)(TLOW - 1));
        int i0 = (int)floorf(src); int i1 = (i0 + 1 < TLOW) ? i0 + 1 : TLOW - 1;
        float w = src - (float)i0;
        interp[(size_t)b * TT + t] = xlow[b * TLOW + i0] * (1.f - w) + xlow[b * TLOW + i1] * w;
    }
}

// ---------------- K2: persistent GRU recurrence ----------------
// grid: 32 blocks x 768 threads (12 waves). blocks 0-15 = layer0 (32 h each),
// 16-31 = layer1. 16 publishers per layer (vs r6's 32), weights spill-proof:
//  L0 wave (g, mt, kh): 10 half8 = 40 VGPR.  L1 wave (g, isH, mt): 16 half8 = 64 VGPR.
// Pollers: L0 wv3 (h0 edge); L1 wv2 (h0 prefetch) + wv3 (h1 edge). Cell: wv0,wv1.
__global__ __launch_bounds__(768, 1) void k_rnn(
    const float* __restrict__ mel, const float* __restrict__ gsx,
    const float* __restrict__ convout, const float* __restrict__ interp,
    const float* __restrict__ wih0, const float* __restrict__ whh0,
    const float* __restrict__ bih0, const float* __restrict__ bhh0,
    const float* __restrict__ wih1, const float* __restrict__ whh1,
    const float* __restrict__ bih1, const float* __restrict__ bhh1,
    unsigned long long* __restrict__ h0buf, unsigned long long* __restrict__ h1buf)
{
    const int tid = threadIdx.x;
    const int wv = tid >> 6;          // 0..11
    const int lane = tid & 63;
    const int lm = lane & 15, lk = lane >> 4;
    const int g = wv >> 2;            // gate (r,z,n)
    const int sub = wv & 3;
    const bool isL0 = (blockIdx.x < 16);
    const int cbid = isL0 ? blockIdx.x : (blockIdx.x - 16);
    const int cb = cbid * 32;                  // h-index chunk base (32 per block)

    __shared__ float exch[3][3][32][9];        // [gate][X/Ha/Hb][row][batch(pad 9)]
    __shared__ __align__(16) unsigned short xv[2][16][136];  // L0 input, double-buffered
    __shared__ unsigned long long stX[8 * 129]; // staged h0 slot (L1 x-part)
    __shared__ unsigned long long stH[8 * 129]; // staged edge slot (L0: h0; L1: h1)

    // cell lanes (wv0,wv1): batch bb = lane>>3, rows i0 = wv*16 + (lane&7)*2 (+0,+1)
    const int cbb = lane >> 3;
    const int ci0 = wv * 16 + (lane & 7) * 2;  // valid for wv<2
    float hr0 = 0.f, hr1 = 0.f;
    float bi0[3], bi1[3], bh0[3], bh1[3];
    if (wv < 2) {
        const float* bi = isL0 ? bih0 : bih1;
        const float* bh = isL0 ? bhh0 : bhh1;
        #pragma unroll
        for (int gg = 0; gg < 3; gg++) {
            bi0[gg] = bi[gg * 512 + cb + ci0];     bi1[gg] = bi[gg * 512 + cb + ci0 + 1];
            bh0[gg] = bh[gg * 512 + cb + ci0];     bh1[gg] = bh[gg * 512 + cb + ci0 + 1];
        }
    }
    for (int i = tid; i < 2 * 16 * 136; i += 768) (&xv[0][0][0])[i] = 0;

    // publish h[-1] = 0 for own chunk (slot 0): wv0,wv1 u32 stores
    if (wv < 2) {
        unsigned long long* buf = isL0 ? h0buf : h1buf;
        unsigned int* o32 = (unsigned int*)buf + (size_t)cbb * 256 + cbid * 16 + wv * 8 + (lane & 7);
        __hip_atomic_store(o32, 0u, __ATOMIC_RELAXED, __HIP_MEMORY_SCOPE_AGENT);
    }

    if (isL0) {
        // roles: mt = sub>>1 (M-tile), kh = sub&1 (K-half)
        const int mt = sub >> 1, kh = sub & 1;
        const int row = g * 512 + cb + mt * 16 + lm;
        // kh0: wf[0..3] = wih0 (K 0..127, cols>=102 zero), wf[4..9] = whh0 frags 0..5
        // kh1: wf[0..9] = whh0 frags 6..15
        half8 wf[10];
        #pragma unroll
        for (int q = 0; q < 10; q++) {
            #pragma unroll
            for (int j = 0; j < 8; j++) {
                float v;
                if (kh == 0) {
                    if (q < 4) { int k = q * 32 + lk * 8 + j; v = (k < 102) ? wih0[(size_t)row * 102 + k] : 0.f; }
                    else       { int k = (q - 4) * 32 + lk * 8 + j; v = whh0[(size_t)row * 512 + k]; }
                } else       { int k = (q + 6) * 32 + lk * 8 + j; v = whh0[(size_t)row * 512 + k]; }
                wf[q][j] = (_Float16)v;
            }
        }
        // initial xv[0] = x(0)
        {
            float pf[2];
            #pragma unroll
            for (int u = 0; u < 2; u++) {
                int e = tid + 768 * u; float v = 0.f;
                if (e < 816) {
                    int bb = e / 102, k = e - 102 * bb;
                    if (k < 80)       v = mel[((size_t)bb * TMEL + 0) * NMEL + k];
                    else if (k < 100) v = convout[((size_t)bb * TLOW + 0) * LC + (k - 80)];
                    else if (k == 100) v = interp[(size_t)bb * TT + 0];
                    else               v = gsx[(size_t)bb * TT + 0];
                }
                pf[u] = v;
            }
            #pragma unroll
            for (int u = 0; u < 2; u++) {
                int e = tid + 768 * u;
                if (e < 816) { int bb = e / 102, k = e - 102 * bb; xv[0][bb][k] = f2h_bits(pf[u]); }
            }
        }
        __syncthreads();

        for (int t = 0; t < TT; t++) {
            // prefetch x(t+1): loads fly during the poll
            int tn = (t + 1 < TT) ? (t + 1) : (TT - 1);
            int tmi = tn / 100, tli = tn / 10;
            float pf[2];
            #pragma unroll
            for (int u = 0; u < 2; u++) {
                int e = tid + 768 * u; float v = 0.f;
                if (e < 816) {
                    int bb = e / 102, k = e - 102 * bb;
                    if (k < 80)       v = mel[((size_t)bb * TMEL + tmi) * NMEL + k];
                    else if (k < 100) v = convout[((size_t)bb * TLOW + tli) * LC + (k - 80)];
                    else if (k == 100) v = interp[(size_t)bb * TT + tn];
                    else               v = gsx[(size_t)bb * TT + tn];
                }
                pf[u] = v;
            }

            if (wv == 3) poll_stage(h0buf + (size_t)t * 1024, lane, stH);
            __syncthreads();   // B1: stH ready

            if (kh == 0) {
                f32x4 aX = {0.f, 0.f, 0.f, 0.f}, aH = {0.f, 0.f, 0.f, 0.f};
                #pragma unroll
                for (int q = 0; q < 4; q++) {
                    half8 xf = *(const half8*)&xv[t & 1][lm][q * 32 + lk * 8];
                    aX = mfma(wf[q], xf, aX);
                }
                #pragma unroll
                for (int q = 0; q < 6; q++) aH = mfma(wf[4 + q], ldsfrag(stH, lane, q), aH);
                if (lm < 8) {
                    #pragma unroll
                    for (int r2 = 0; r2 < 4; r2++) {
                        exch[g][0][mt * 16 + lk * 4 + r2][lm] = aX[r2];
                        exch[g][1][mt * 16 + lk * 4 + r2][lm] = aH[r2];
                    }
                }
            } else {
                f32x4 aH = {0.f, 0.f, 0.f, 0.f}, aH2 = {0.f, 0.f, 0.f, 0.f};
                #pragma unroll
                for (int q = 0; q < 5; q++) aH = mfma(wf[q], ldsfrag(stH, lane, 6 + q), aH);
                #pragma unroll
                for (int q = 5; q < 10; q++) aH2 = mfma(wf[q], ldsfrag(stH, lane, 6 + q), aH2);
                aH = aH + aH2;
                if (lm < 8) {
                    #pragma unroll
                    for (int r2 = 0; r2 < 4; r2++) exch[g][2][mt * 16 + lk * 4 + r2][lm] = aH[r2];
                }
            }
            // write next x buffer (dbuf)
            #pragma unroll
            for (int u = 0; u < 2; u++) {
                int e = tid + 768 * u;
                if (e < 816) { int bb = e / 102, k = e - 102 * bb; xv[(t + 1) & 1][bb][k] = f2h_bits(pf[u]); }
            }
            __syncthreads();   // B2: exch ready
            if (wv < 2) {
                float r0 = sigf(exch[0][0][ci0][cbb] + exch[0][1][ci0][cbb] + exch[0][2][ci0][cbb] + bi0[0] + bh0[0]);
                float z0 = sigf(exch[1][0][ci0][cbb] + exch[1][1][ci0][cbb] + exch[1][2][ci0][cbb] + bi0[1] + bh0[1]);
                float n0 = tanhf_(exch[2][0][ci0][cbb] + bi0[2]
                                  + r0 * (exch[2][1][ci0][cbb] + exch[2][2][ci0][cbb] + bh0[2]));
                hr0 = (1.f - z0) * n0 + z0 * hr0;
                int i1 = ci0 + 1;
                float r1 = sigf(exch[0][0][i1][cbb] + exch[0][1][i1][cbb] + exch[0][2][i1][cbb] + bi1[0] + bh1[0]);
                float z1 = sigf(exch[1][0][i1][cbb] + exch[1][1][i1][cbb] + exch[1][2][i1][cbb] + bi1[1] + bh1[1]);
                float n1 = tanhf_(exch[2][0][i1][cbb] + bi1[2]
                                  + r1 * (exch[2][1][i1][cbb] + exch[2][2][i1][cbb] + bh1[2]));
                hr1 = (1.f - z1) * n1 + z1 * hr1;
                unsigned int pk = (unsigned int)f2h_bits(hr0) | ((unsigned int)f2h_bits(hr1) << 16);
                unsigned int* o32 = (unsigned int*)(h0buf + (size_t)(t + 1) * 1024)
                                  + (size_t)cbb * 256 + cbid * 16 + wv * 8 + (lane & 7);
                __hip_atomic_store(o32, pk, __ATOMIC_RELAXED, __HIP_MEMORY_SCOPE_AGENT);
            }
        }
    } else {
        // roles: isH = sub>>1 (x-part from h0 vs h-part from h1), mt = sub&1
        const int isH = sub >> 1, mt = sub & 1;
        const int row = g * 512 + cb + mt * 16 + lm;
        const float* wsrc = isH ? whh1 : wih1;
        half8 wf[16];
        #pragma unroll
        for (int q = 0; q < 16; q++)
            #pragma unroll
            for (int j = 0; j < 8; j++)
                wf[q][j] = (_Float16)wsrc[(size_t)row * 512 + q * 32 + lk * 8 + j];
        __syncthreads();

        for (int t = 0; t < TT; t++) {
            // parallel polls: wv2 stages h0[t] (slot t+1; L0 ahead), wv3 stages h1[t-1]
            if (wv == 2)      poll_stage(h0buf + (size_t)(t + 1) * 1024, lane, stX);
            else if (wv == 3) poll_stage(h1buf + (size_t)t * 1024,       lane, stH);
            __syncthreads();   // B1

            const unsigned long long* src = isH ? stH : stX;
            f32x4 a0 = {0.f, 0.f, 0.f, 0.f}, a1 = {0.f, 0.f, 0.f, 0.f};
            #pragma unroll
            for (int q = 0; q < 8; q++) a0 = mfma(wf[q], ldsfrag(src, lane, q), a0);
            #pragma unroll
            for (int q = 8; q < 16; q++) a1 = mfma(wf[q], ldsfrag(src, lane, q), a1);
            f32x4 acc = a0 + a1;
            if (lm < 8) {
                #pragma unroll
                for (int r2 = 0; r2 < 4; r2++) exch[g][isH][mt * 16 + lk * 4 + r2][lm] = acc[r2];
            }
            __syncthreads();   // B2
            if (wv < 2) {
                float r0 = sigf(exch[0][0][ci0][cbb] + exch[0][1][ci0][cbb] + bi0[0] + bh0[0]);
                float z0 = sigf(exch[1][0][ci0][cbb] + exch[1][1][ci0][cbb] + bi0[1] + bh0[1]);
                float n0 = tanhf_(exch[2][0][ci0][cbb] + bi0[2] + r0 * (exch[2][1][ci0][cbb] + bh0[2]));
                hr0 = (1.f - z0) * n0 + z0 * hr0;
                int i1 = ci0 + 1;
                float r1 = sigf(exch[0][0][i1][cbb] + exch[0][1][i1][cbb] + bi1[0] + bh1[0]);
                float z1 = sigf(exch[1][0][i1][cbb] + exch[1][1][i1][cbb] + bi1[1] + bh1[1]);
                float n1 = tanhf_(exch[2][0][i1][cbb] + bi1[2] + r1 * (exch[2][1][i1][cbb] + bh1[2]));
                hr1 = (1.f - z1) * n1 + z1 * hr1;
                unsigned int pk = (unsigned int)f2h_bits(hr0) | ((unsigned int)f2h_bits(hr1) << 16);
                unsigned int* o32 = (unsigned int*)(h1buf + (size_t)(t + 1) * 1024)
                                  + (size_t)cbb * 256 + cbid * 16 + wv * 8 + (lane & 7);
                __hip_atomic_store(o32, pk, __ATOMIC_RELAXED, __HIP_MEMORY_SCOPE_AGENT);
            }
        }
    }
}

// ---------------- K3: fused head ----------------
__global__ __launch_bounds__(256) void k_final(
    const unsigned long long* __restrict__ h1buf,
    const unsigned short* __restrict__ prew16, const float* __restrict__ pre_b,
    const unsigned short* __restrict__ outw16, const float* __restrict__ out_b,
    float* __restrict__ out)
{
    int blk = blockIdx.x; int b = blk / 125; int tb = (blk - b * 125) * 64;
    int tid = threadIdx.x; int wv = tid >> 6; int l = tid & 63;
    int lm = l & 15, lk = l >> 4;

    half8 af[16];
    int trow = tb + wv * 16 + lm;
    const unsigned long long* abase = h1buf + ((size_t)(trow + 1) * 8 + b) * 128;
    #pragma unroll
    for (int kt = 0; kt < 16; kt++)
        af[kt] = mkfrag(abase[kt * 8 + lk * 2], abase[kt * 8 + lk * 2 + 1]);

    f32x4 acc[16];
    #pragma unroll
    for (int nt = 0; nt < 16; nt++) {
        f32x4 z = {0.f, 0.f, 0.f, 0.f}; acc[nt] = z;
        #pragma unroll
        for (int kt = 0; kt < 16; kt++) {
            int n = nt * 16 + lm; int k = kt * 32 + lk * 8;
            half8 bw = *(const half8*)&prew16[(size_t)n * HD + k];
            acc[nt] = mfma(af[kt], bw, acc[nt]);
        }
    }
    __shared__ __align__(16) unsigned short pt[64][264];
    #pragma unroll
    for (int nt = 0; nt < 16; nt++) {
        float pb = pre_b[nt * 16 + lm];
        #pragma unroll
        for (int r2 = 0; r2 < 4; r2++)
            pt[wv * 16 + lk * 4 + r2][nt * 16 + lm] = f2h_bits(tanhf_(acc[nt][r2] + pb));
    }
    __syncthreads();
    f32x4 a2[2];
    { f32x4 z = {0.f, 0.f, 0.f, 0.f}; a2[0] = z; a2[1] = z; }
    #pragma unroll
    for (int kt = 0; kt < 8; kt++) {
        half8 pa = *(const half8*)&pt[wv * 16 + lm][kt * 32 + lk * 8];
        #pragma unroll
        for (int nt = 0; nt < 2; nt++) {
            int n = nt * 16 + lm;
            half8 bw = (n < NSS) ? *(const half8*)&outw16[(size_t)n * NPRE + kt * 32 + lk * 8]
                                 : mkfrag(0ull, 0ull);
            a2[nt] = mfma(pa, bw, a2[nt]);
        }
    }
    #pragma unroll
    for (int nt = 0; nt < 2; nt++) {
        int n = nt * 16 + lm;
        if (n < NSS) {
            float ob = out_b[n];
            #pragma unroll
            for (int r2 = 0; r2 < 4; r2++) {
                int t = tb + wv * 16 + lk * 4 + r2;
                out[((size_t)b * TT + t) * NSS + n] = a2[nt][r2] + ob;
            }
        }
    }
}

// ---------------- launch ----------------
extern "C" void kernel_launch(void* const* d_in, const int* in_sizes, int n_in,
                              void* d_out, int out_size, void* d_ws, size_t ws_size,
                              hipStream_t stream) {
    const float* mel  = (const float*)d_in[0];
    const float* xlow = (const float*)d_in[1];
    const float* gsx  = (const float*)d_in[2];
    const float* cw0  = (const float*)d_in[3];
    const float* cb0  = (const float*)d_in[4];
    const float* cw1  = (const float*)d_in[5];
    const float* cb1  = (const float*)d_in[6];
    const float* cw2  = (const float*)d_in[7];
    const float* cb2  = (const float*)d_in[8];
    const float* wih0 = (const float*)d_in[9];
    const float* whh0 = (const float*)d_in[10];
    const float* bih0 = (const float*)d_in[11];
    const float* bhh0 = (const float*)d_in[12];
    const float* wih1 = (const float*)d_in[13];
    const float* whh1 = (const float*)d_in[14];
    const float* bih1 = (const float*)d_in[15];
    const float* bhh1 = (const float*)d_in[16];
    const float* prew = (const float*)d_in[17];
    const float* preb = (const float*)d_in[18];
    const float* outw = (const float*)d_in[19];
    const float* outb = (const float*)d_in[20];

    size_t needed = 2 * HB_BYTES + CONV_BYTES + INTERP_BYTES + PREW16_BYTES + OUTW16_BYTES;
    if (ws_size < needed) return;

    char* ws = (char*)d_ws;
    unsigned long long* h0buf = (unsigned long long*)ws;
    unsigned long long* h1buf = (unsigned long long*)(ws + HB_BYTES);
    float* convout = (float*)(ws + 2 * HB_BYTES);
    float* interp  = (float*)(ws + 2 * HB_BYTES + CONV_BYTES);
    unsigned short* prew16 = (unsigned short*)(ws + 2 * HB_BYTES + CONV_BYTES + INTERP_BYTES);
    unsigned short* outw16 = (unsigned short*)(ws + 2 * HB_BYTES + CONV_BYTES + INTERP_BYTES + PREW16_BYTES);

    // sentinel-init both h broadcast buffers (0xFF.. = NaN fp16 pairs / 0xFFFFFFFF u32 sentinel)
    hipMemsetAsync(ws, 0xFF, 2 * HB_BYTES, stream);

    k_prep<<<(NPRE * HD + 255) / 256, 256, 0, stream>>>(prew, outw, prew16, outw16);
    k_conv<<<32, 256, 0, stream>>>(xlow, cw0, cb0, cw1, cb1, cw2, cb2, convout, interp);
    k_rnn<<<32, 768, 0, stream>>>(mel, gsx, convout, interp,
                                  wih0, whh0, bih0, bhh0,
                                  wih1, whh1, bih1, bhh1,
                                  h0buf, h1buf);
    k_final<<<1000, 256, 0, stream>>>(h1buf, prew16, preb, outw16, outb, (float*)d_out);
}